// Round 1
// baseline (22003.043 us; speedup 1.0000x reference)
//
#include <hip/hip_runtime.h>
#include <cstddef>

#define TOK   8192
#define DIMD  768
#define NH    12
#define DHD   64
#define SEQ   512
#define NB_   16
#define FFD   3072
#define NEXP  4
#define CCLS  10
#define CHUNK 2048

// ---------------- workspace layout (float units) ----------------
static const size_t OFF_X    = 0;
static const size_t OFF_F    = OFF_X   + (size_t)TOK*DIMD;      // 6,291,456
static const size_t OFF_QKV  = OFF_F   + (size_t)TOK*DIMD;
static const size_t OFF_H    = OFF_QKV + (size_t)TOK*3*DIMD;
static const size_t OFF_G    = OFF_H   + (size_t)CHUNK*2*FFD;   // also attn-out: TOK*DIMD == CHUNK*FFD
static const size_t OFF_REP  = OFF_G   + (size_t)CHUNK*FFD;
static const size_t OFF_HCLS = OFF_REP + (size_t)NB_*DIMD;
static const size_t OFF_STAT = OFF_HCLS+ (size_t)NB_*DIMD;      // sums[4] + pad[4]
static const size_t OFF_INT  = OFF_STAT+ 8;                     // ints: cntA[2],cntB[2],cntE[4],offs[5],cursor[4] (24 slots)
static const size_t OFF_AUX  = OFF_INT + 24;                    // 1 float (NOT covered by per-layer memset)
static const size_t OFF_EID  = OFF_AUX + 1;                     // TOK ints
static const size_t OFF_PERM = OFF_EID + TOK;                   // TOK ints

// ---------------- embedding ----------------
__global__ __launch_bounds__(256) void k_embed(const int* __restrict__ ids,
                                               const float* __restrict__ te,
                                               const float* __restrict__ pe,
                                               float* __restrict__ x)
{
    int i = blockIdx.x * 256 + threadIdx.x;            // float4 index
    const int nd4 = DIMD / 4;
    if (i >= TOK * nd4) return;
    int t = i / nd4, d4 = i % nd4;
    int s = t % SEQ;
    int id = ids[t];
    float4 a = ((const float4*)(te + (size_t)id * DIMD))[d4];
    float4 b = ((const float4*)(pe + (size_t)s  * DIMD))[d4];
    float4 o; o.x = a.x + b.x; o.y = a.y + b.y; o.z = a.z + b.z; o.w = a.w + b.w;
    ((float4*)(x + (size_t)t * DIMD))[d4] = o;
}

// ---------------- fp32 tiled GEMM: C[m,n] = sum_k A[m,k]*W[n,k] + bias[n] ----------------
#define BM 64
#define BN 64
#define BKK 16
#define LDT 68

__global__ __launch_bounds__(256) void k_gemm(const float* __restrict__ A,
                                              const float* __restrict__ W,
                                              const float* __restrict__ bias,
                                              float* __restrict__ C,
                                              int M, int N, int K)
{
    __shared__ float As[BKK][LDT];
    __shared__ float Ws[BKK][LDT];
    const int tid = threadIdx.x;
    const int n0 = blockIdx.x * BN;
    const int m0 = blockIdx.y * BM;
    const int tr = tid >> 2, tk = tid & 3;
    const int tm = tid >> 4, tn = tid & 15;
    float acc[4][4] = {{0.f,0.f,0.f,0.f},{0.f,0.f,0.f,0.f},{0.f,0.f,0.f,0.f},{0.f,0.f,0.f,0.f}};
    const float* Ap = A + (size_t)(m0 + tr) * K + tk * 4;
    const float* Wp = W + (size_t)(n0 + tr) * K + tk * 4;
    for (int k0 = 0; k0 < K; k0 += BKK) {
        float4 av = *(const float4*)(Ap + k0);
        float4 wv = *(const float4*)(Wp + k0);
        __syncthreads();
        As[tk*4+0][tr] = av.x; As[tk*4+1][tr] = av.y; As[tk*4+2][tr] = av.z; As[tk*4+3][tr] = av.w;
        Ws[tk*4+0][tr] = wv.x; Ws[tk*4+1][tr] = wv.y; Ws[tk*4+2][tr] = wv.z; Ws[tk*4+3][tr] = wv.w;
        __syncthreads();
#pragma unroll
        for (int kk = 0; kk < BKK; ++kk) {
            float4 a4 = *(const float4*)&As[kk][tm*4];
            float4 w4 = *(const float4*)&Ws[kk][tn*4];
            acc[0][0] += a4.x*w4.x; acc[0][1] += a4.x*w4.y; acc[0][2] += a4.x*w4.z; acc[0][3] += a4.x*w4.w;
            acc[1][0] += a4.y*w4.x; acc[1][1] += a4.y*w4.y; acc[1][2] += a4.y*w4.z; acc[1][3] += a4.y*w4.w;
            acc[2][0] += a4.z*w4.x; acc[2][1] += a4.z*w4.y; acc[2][2] += a4.z*w4.z; acc[2][3] += a4.z*w4.w;
            acc[3][0] += a4.w*w4.x; acc[3][1] += a4.w*w4.y; acc[3][2] += a4.w*w4.z; acc[3][3] += a4.w*w4.w;
        }
    }
    float4 b4 = *(const float4*)(bias + n0 + tn*4);
#pragma unroll
    for (int i = 0; i < 4; ++i) {
        float4 o;
        o.x = acc[i][0] + b4.x; o.y = acc[i][1] + b4.y; o.z = acc[i][2] + b4.z; o.w = acc[i][3] + b4.w;
        *(float4*)(C + (size_t)(m0 + tm*4 + i) * N + n0 + tn*4) = o;
    }
}

// ---------------- MoE gathered/scattered GEMM (per expert e, per 2048-row chunk) ----------------
// gatherA=1: A rows = x[perm[...]], C rows linear into h-chunk.
// gatherA=0: A rows linear from g-chunk, C rows scattered to f[perm[...]] (ld = Cld).
__global__ __launch_bounds__(256) void k_gemm_moe(const float* __restrict__ A,
                                                  const float* __restrict__ W,
                                                  const float* __restrict__ bias,
                                                  float* __restrict__ C,
                                                  const int* __restrict__ perm,
                                                  const int* __restrict__ offsets,
                                                  int e, int chunk, int N, int K,
                                                  int gatherA, int Cld)
{
    __shared__ float As[BKK][LDT];
    __shared__ float Ws[BKK][LDT];
    __shared__ int   toks[BM];
    const int base = offsets[e];
    const int cnt  = offsets[e + 1] - base;
    const int r0   = chunk * CHUNK + blockIdx.y * BM;   // row within this expert
    if (r0 >= cnt) return;
    const int tid = threadIdx.x;
    if (tid < BM) {
        int rg = r0 + tid;
        toks[tid] = perm[base + (rg < cnt ? rg : cnt - 1)];
    }
    __syncthreads();
    const int n0 = blockIdx.x * BN;
    const int tr = tid >> 2, tk = tid & 3;
    const int tm = tid >> 4, tn = tid & 15;
    const int lrow = blockIdx.y * BM;                   // chunk-local base row
    const int arow = gatherA ? toks[tr] : (lrow + tr);
    float acc[4][4] = {{0.f,0.f,0.f,0.f},{0.f,0.f,0.f,0.f},{0.f,0.f,0.f,0.f},{0.f,0.f,0.f,0.f}};
    const float* Ap = A + (size_t)arow * K + tk * 4;
    const float* Wp = W + (size_t)(n0 + tr) * K + tk * 4;
    for (int k0 = 0; k0 < K; k0 += BKK) {
        float4 av = *(const float4*)(Ap + k0);
        float4 wv = *(const float4*)(Wp + k0);
        __syncthreads();
        As[tk*4+0][tr] = av.x; As[tk*4+1][tr] = av.y; As[tk*4+2][tr] = av.z; As[tk*4+3][tr] = av.w;
        Ws[tk*4+0][tr] = wv.x; Ws[tk*4+1][tr] = wv.y; Ws[tk*4+2][tr] = wv.z; Ws[tk*4+3][tr] = wv.w;
        __syncthreads();
#pragma unroll
        for (int kk = 0; kk < BKK; ++kk) {
            float4 a4 = *(const float4*)&As[kk][tm*4];
            float4 w4 = *(const float4*)&Ws[kk][tn*4];
            acc[0][0] += a4.x*w4.x; acc[0][1] += a4.x*w4.y; acc[0][2] += a4.x*w4.z; acc[0][3] += a4.x*w4.w;
            acc[1][0] += a4.y*w4.x; acc[1][1] += a4.y*w4.y; acc[1][2] += a4.y*w4.z; acc[1][3] += a4.y*w4.w;
            acc[2][0] += a4.z*w4.x; acc[2][1] += a4.z*w4.y; acc[2][2] += a4.z*w4.z; acc[2][3] += a4.z*w4.w;
            acc[3][0] += a4.w*w4.x; acc[3][1] += a4.w*w4.y; acc[3][2] += a4.w*w4.z; acc[3][3] += a4.w*w4.w;
        }
    }
    float4 b4 = *(const float4*)(bias + n0 + tn*4);
#pragma unroll
    for (int i = 0; i < 4; ++i) {
        float4 o;
        o.x = acc[i][0] + b4.x; o.y = acc[i][1] + b4.y; o.z = acc[i][2] + b4.z; o.w = acc[i][3] + b4.w;
        int r = tm*4 + i;
        if (gatherA) {
            *(float4*)(C + (size_t)(lrow + r) * N + n0 + tn*4) = o;     // linear into h chunk
        } else {
            int rg = r0 + r;
            if (rg < cnt) {
                int tok = toks[r];
                *(float4*)(C + (size_t)tok * Cld + n0 + tn*4) = o;      // scatter to f[token]
            }
        }
    }
}

// ---------------- GLU: g = a * silu(b), [a,b] = split(h) ----------------
__global__ __launch_bounds__(256) void k_glu(const float* __restrict__ h, float* __restrict__ g)
{
    int i = blockIdx.x * 256 + threadIdx.x;             // float4 index over CHUNK*FFD
    const int nf4 = FFD / 4;
    if (i >= CHUNK * nf4) return;
    int r = i / nf4, j4 = i % nf4;
    float4 a = ((const float4*)(h + (size_t)r * 2 * FFD))[j4];
    float4 b = ((const float4*)(h + (size_t)r * 2 * FFD + FFD))[j4];
    float4 o;
    o.x = a.x * (b.x / (1.f + __expf(-b.x)));
    o.y = a.y * (b.y / (1.f + __expf(-b.y)));
    o.z = a.z * (b.z / (1.f + __expf(-b.z)));
    o.w = a.w * (b.w / (1.f + __expf(-b.w)));
    ((float4*)g)[i] = o;
}

// ---------------- attention (flash-style, one thread per q-row) ----------------
__global__ __launch_bounds__(128) void k_attn(const float* __restrict__ qkv, float* __restrict__ out)
{
    const int bh = blockIdx.x;
    const int b = bh / NH, h = bh % NH;
    const int qrow = blockIdx.y * 128 + threadIdx.x;    // 0..511
    const int t = b * SEQ + qrow;
    const float* qp = qkv + (size_t)t * 3 * DIMD + h * DHD;
    float q[DHD], o[DHD];
#pragma unroll
    for (int d = 0; d < DHD; d += 4) {
        float4 v = *(const float4*)(qp + d);
        q[d] = v.x; q[d+1] = v.y; q[d+2] = v.z; q[d+3] = v.w;
        o[d] = 0.f; o[d+1] = 0.f; o[d+2] = 0.f; o[d+3] = 0.f;
    }
    float m = -3.0e38f, l = 0.f;
    __shared__ float Ks[32][DHD];
    __shared__ float Vs[32][DHD];
    for (int kt = 0; kt < SEQ; kt += 32) {
        __syncthreads();
        for (int idx = threadIdx.x; idx < 32 * (DHD/4); idx += 128) {
            int kk = idx / (DHD/4), d4 = idx % (DHD/4);
            int t2 = b * SEQ + kt + kk;
            const float* kp = qkv + (size_t)t2 * 3 * DIMD + DIMD + h * DHD;
            ((float4*)Ks[kk])[d4] = ((const float4*)kp)[d4];
            ((float4*)Vs[kk])[d4] = ((const float4*)(kp + DIMD))[d4];
        }
        __syncthreads();
        for (int kk = 0; kk < 32; ++kk) {
            float s0=0.f, s1=0.f, s2=0.f, s3=0.f;
#pragma unroll
            for (int d = 0; d < DHD; d += 4) {
                s0 += q[d+0] * Ks[kk][d+0];
                s1 += q[d+1] * Ks[kk][d+1];
                s2 += q[d+2] * Ks[kk][d+2];
                s3 += q[d+3] * Ks[kk][d+3];
            }
            float sv = (s0 + s1 + s2 + s3) * 0.125f;
            float nm = fmaxf(m, sv);
            float c = __expf(m - nm);
            float p = __expf(sv - nm);
            l = l * c + p;
#pragma unroll
            for (int d = 0; d < DHD; ++d) o[d] = o[d] * c + p * Vs[kk][d];
            m = nm;
        }
    }
    float inv = 1.f / l;
    float* op = out + (size_t)t * DIMD + h * DHD;
#pragma unroll
    for (int d = 0; d < DHD; d += 4) {
        float4 v; v.x = o[d]*inv; v.y = o[d+1]*inv; v.z = o[d+2]*inv; v.w = o[d+3]*inv;
        *(float4*)(op + d) = v;
    }
}

// ---------------- fused residual + LayerNorm: x = LN(x + f)*g + b ----------------
__global__ __launch_bounds__(256) void k_ln(float* __restrict__ x, const float* __restrict__ f,
                                            const float* __restrict__ g, const float* __restrict__ b)
{
    const int t = blockIdx.x, tid = threadIdx.x;
    __shared__ float y[DIMD];
    __shared__ float red[256];
    float* xr = x + (size_t)t * DIMD;
    const float* fr = f + (size_t)t * DIMD;
    float s = 0.f;
    for (int d = tid; d < DIMD; d += 256) { float v = xr[d] + fr[d]; y[d] = v; s += v; }
    red[tid] = s; __syncthreads();
    for (int off = 128; off > 0; off >>= 1) { if (tid < off) red[tid] += red[tid + off]; __syncthreads(); }
    const float mean = red[0] * (1.f / DIMD);
    __syncthreads();
    s = 0.f;
    for (int d = tid; d < DIMD; d += 256) { float v = y[d] - mean; s += v * v; }
    red[tid] = s; __syncthreads();
    for (int off = 128; off > 0; off >>= 1) { if (tid < off) red[tid] += red[tid + off]; __syncthreads(); }
    const float rstd = 1.f / sqrtf(red[0] * (1.f / DIMD) + 1e-5f);
    for (int d = tid; d < DIMD; d += 256) xr[d] = (y[d] - mean) * rstd * g[d] + b[d];
}

// ---------------- MoE gating (one wave per token) ----------------
__global__ __launch_bounds__(64) void k_gate(const float* __restrict__ x,
                                             const float* __restrict__ gAw, const float* __restrict__ gAb,
                                             const float* __restrict__ gBw, const float* __restrict__ gBb,
                                             float* __restrict__ sums, int* __restrict__ cnts,
                                             int* __restrict__ e_id)
{
    const int t = blockIdx.x;
    const int lane = threadIdx.x;
    const float* xr = x + (size_t)t * DIMD;
    float a0=0.f, a1=0.f, b0=0.f, b1=0.f;
    for (int d = lane; d < DIMD; d += 64) {
        float v = xr[d];
        a0 += v * gAw[d]; a1 += v * gAw[DIMD + d];
        b0 += v * gBw[d]; b1 += v * gBw[DIMD + d];
    }
    for (int off = 32; off > 0; off >>= 1) {
        a0 += __shfl_down(a0, off); a1 += __shfl_down(a1, off);
        b0 += __shfl_down(b0, off); b1 += __shfl_down(b1, off);
    }
    if (lane == 0) {
        a0 += gAb[0]; a1 += gAb[1]; b0 += gBb[0]; b1 += gBb[1];
        int iA = (a1 > a0) ? 1 : 0;
        int iB = (b1 > b0) ? 1 : 0;
        float mA = fmaxf(a0, a1); float eA0 = __expf(a0 - mA), eA1 = __expf(a1 - mA);
        float dA = eA0 + eA1;     float pA0 = eA0 / dA, pA1 = eA1 / dA;
        float mB = fmaxf(b0, b1); float eB0 = __expf(b0 - mB), eB1 = __expf(b1 - mB);
        float dB = eB0 + eB1;     float pB0 = eB0 / dB, pB1 = eB1 / dB;
        atomicAdd(sums + 0, pA0); atomicAdd(sums + 1, pA1);
        atomicAdd(sums + 2, pB0); atomicAdd(sums + 3, pB1);
        atomicAdd(cnts + iA, 1);  atomicAdd(cnts + 2 + iB, 1);
        int e = iA * 2 + iB;
        e_id[t] = e;
        atomicAdd(cnts + 4 + e, 1);
    }
}

__global__ void k_offsets(const int* __restrict__ cntE, int* __restrict__ offs, int* __restrict__ cursor)
{
    if (threadIdx.x == 0) {
        int a = 0;
        for (int e = 0; e < NEXP; ++e) { offs[e] = a; a += cntE[e]; cursor[e] = 0; }
        offs[NEXP] = a;
    }
}

__global__ __launch_bounds__(256) void k_scatter(const int* __restrict__ e_id, const int* __restrict__ offs,
                                                 int* __restrict__ cursor, int* __restrict__ perm)
{
    int t = blockIdx.x * 256 + threadIdx.x;
    if (t >= TOK) return;
    int e = e_id[t];
    int p = atomicAdd(cursor + e, 1);
    perm[offs[e] + p] = t;
}

__global__ void k_aux(const float* __restrict__ sums, const int* __restrict__ cnts, float* __restrict__ aux_acc)
{
    if (threadIdx.x == 0) {
        const float invT2 = 1.f / ((float)TOK * (float)TOK);
        float aA = 2.f * (sums[0] * (float)cnts[0] + sums[1] * (float)cnts[1]) * invT2;
        float aB = 2.f * (sums[2] * (float)cnts[2] + sums[3] * (float)cnts[3]) * invT2;
        *aux_acc += aA + aB;
    }
}

// ---------------- classifier head ----------------
__global__ __launch_bounds__(256) void k_rep(const float* __restrict__ x, float* __restrict__ rep)
{
    int i = blockIdx.x * 256 + threadIdx.x;
    if (i >= NB_ * DIMD) return;
    int b = i / DIMD, d = i % DIMD;
    float s = 0.f;
    for (int q = 0; q < SEQ; ++q) s += x[((size_t)b * SEQ + q) * DIMD + d];
    rep[i] = s * (1.f / SEQ);
}

__global__ __launch_bounds__(256) void k_cls1(const float* __restrict__ rep, const float* __restrict__ cW1,
                                              const float* __restrict__ cB1, float* __restrict__ hcls)
{
    int w = blockIdx.x * 4 + (threadIdx.x >> 6);
    int lane = threadIdx.x & 63;
    if (w >= NB_ * DIMD) return;
    int b = w / DIMD, i = w % DIMD;
    float s = 0.f;
    for (int d = lane; d < DIMD; d += 64) s += rep[b * DIMD + d] * cW1[(size_t)i * DIMD + d];
    for (int off = 32; off > 0; off >>= 1) s += __shfl_down(s, off);
    if (lane == 0) hcls[w] = fmaxf(s + cB1[i], 0.f);
}

__global__ __launch_bounds__(256) void k_cls2(const float* __restrict__ hcls, const float* __restrict__ cW2,
                                              const float* __restrict__ cB2, float* __restrict__ out)
{
    int w = blockIdx.x * 4 + (threadIdx.x >> 6);
    int lane = threadIdx.x & 63;
    if (w >= NB_ * CCLS) return;
    int b = w / CCLS, c = w % CCLS;
    float s = 0.f;
    for (int d = lane; d < DIMD; d += 64) s += hcls[b * DIMD + d] * cW2[(size_t)c * DIMD + d];
    for (int off = 32; off > 0; off >>= 1) s += __shfl_down(s, off);
    if (lane == 0) out[w] = s + cB2[c];
}

__global__ void k_writeaux(const float* __restrict__ aux_acc, float* __restrict__ out)
{
    if (threadIdx.x == 0) out[NB_ * CCLS] = *aux_acc;
}

// ---------------- host launch ----------------
extern "C" void kernel_launch(void* const* d_in, const int* in_sizes, int n_in,
                              void* d_out, int out_size, void* d_ws, size_t ws_size,
                              hipStream_t stream)
{
    const int*   input_ids = (const int*)  d_in[0];
    const float* tok_emb   = (const float*)d_in[1];
    const float* pos_emb   = (const float*)d_in[2];
    const float* wqkv      = (const float*)d_in[3];
    const float* bqkv      = (const float*)d_in[4];
    const float* wo        = (const float*)d_in[5];
    const float* bo        = (const float*)d_in[6];
    const float* ln1g      = (const float*)d_in[7];
    const float* ln1b      = (const float*)d_in[8];
    const float* ln2g      = (const float*)d_in[9];
    const float* ln2b      = (const float*)d_in[10];
    const float* dW1       = (const float*)d_in[11];
    const float* dB1       = (const float*)d_in[12];
    const float* dW2       = (const float*)d_in[13];
    const float* dB2       = (const float*)d_in[14];
    const float* mW1       = (const float*)d_in[15];
    const float* mB1       = (const float*)d_in[16];
    const float* mW2       = (const float*)d_in[17];
    const float* mB2       = (const float*)d_in[18];
    const float* gAw       = (const float*)d_in[19];
    const float* gAb       = (const float*)d_in[20];
    const float* gBw       = (const float*)d_in[21];
    const float* gBb       = (const float*)d_in[22];
    const float* cW1       = (const float*)d_in[23];
    const float* cB1       = (const float*)d_in[24];
    const float* cW2       = (const float*)d_in[25];
    const float* cB2       = (const float*)d_in[26];

    float* out = (float*)d_out;
    float* ws  = (float*)d_ws;

    float* X    = ws + OFF_X;
    float* F    = ws + OFF_F;
    float* QKV  = ws + OFF_QKV;
    float* Hb   = ws + OFF_H;
    float* G    = ws + OFF_G;     // attn-out and GLU-out (time-shared)
    float* REP  = ws + OFF_REP;
    float* HCLS = ws + OFF_HCLS;
    float* SUMS = ws + OFF_STAT;
    int*   CNTS = (int*)(ws + OFF_INT);       // [0..3] cntA/cntB, [4..7] cntE
    int*   OFFS = CNTS + 8;                   // 5 ints
    int*   CURS = CNTS + 13;                  // 4 ints
    float* AUXP = ws + OFF_AUX;
    int*   EID  = (int*)(ws + OFF_EID);
    int*   PERM = (int*)(ws + OFF_PERM);

    hipMemsetAsync(AUXP, 0, sizeof(float), stream);

    k_embed<<<dim3((TOK * DIMD / 4) / 256), 256, 0, stream>>>(input_ids, tok_emb, pos_emb, X);

    int di = 0, mi = 0;
    for (int l = 0; l < 6; ++l) {
        // QKV projection
        k_gemm<<<dim3(3 * DIMD / BN, TOK / BM), 256, 0, stream>>>(
            X, wqkv + (size_t)l * 3 * DIMD * DIMD, bqkv + (size_t)l * 3 * DIMD, QKV, TOK, 3 * DIMD, DIMD);
        // attention -> G
        k_attn<<<dim3(NB_ * NH, SEQ / 128), 128, 0, stream>>>(QKV, G);
        // output projection -> F
        k_gemm<<<dim3(DIMD / BN, TOK / BM), 256, 0, stream>>>(
            G, wo + (size_t)l * DIMD * DIMD, bo + (size_t)l * DIMD, F, TOK, DIMD, DIMD);
        // x = LN1(x + F)
        k_ln<<<TOK, 256, 0, stream>>>(X, F, ln1g + (size_t)l * DIMD, ln1b + (size_t)l * DIMD);

        if (l == 1 || l == 3 || l == 5) {
            // ---- MoE ----
            hipMemsetAsync(SUMS, 0, (8 + 24) * sizeof(float), stream);   // sums + int region (not aux)
            k_gate<<<TOK, 64, 0, stream>>>(X,
                gAw + (size_t)mi * 2 * DIMD, gAb + (size_t)mi * 2,
                gBw + (size_t)mi * 2 * DIMD, gBb + (size_t)mi * 2,
                SUMS, CNTS, EID);
            k_offsets<<<1, 1, 0, stream>>>(CNTS + 4, OFFS, CURS);
            k_scatter<<<TOK / 256, 256, 0, stream>>>(EID, OFFS, CURS, PERM);
            for (int e = 0; e < NEXP; ++e) {
                const float* w1 = mW1 + ((size_t)mi * NEXP + e) * 2 * FFD * DIMD;
                const float* b1 = mB1 + ((size_t)mi * NEXP + e) * 2 * FFD;
                const float* w2 = mW2 + ((size_t)mi * NEXP + e) * (size_t)DIMD * FFD;
                const float* b2 = mB2 + ((size_t)mi * NEXP + e) * DIMD;
                for (int c = 0; c < TOK / CHUNK; ++c) {
                    k_gemm_moe<<<dim3(2 * FFD / BN, CHUNK / BM), 256, 0, stream>>>(
                        X, w1, b1, Hb, PERM, OFFS, e, c, 2 * FFD, DIMD, 1, 2 * FFD);
                    k_glu<<<dim3((CHUNK * FFD / 4) / 256), 256, 0, stream>>>(Hb, G);
                    k_gemm_moe<<<dim3(DIMD / BN, CHUNK / BM), 256, 0, stream>>>(
                        G, w2, b2, F, PERM, OFFS, e, c, DIMD, FFD, 0, DIMD);
                }
            }
            k_aux<<<1, 1, 0, stream>>>(SUMS, CNTS, AUXP);
            ++mi;
        } else {
            // ---- dense FFN (chunked over tokens) ----
            const float* w1 = dW1 + (size_t)di * 2 * FFD * DIMD;
            const float* b1 = dB1 + (size_t)di * 2 * FFD;
            const float* w2 = dW2 + (size_t)di * (size_t)DIMD * FFD;
            const float* b2 = dB2 + (size_t)di * DIMD;
            for (int c = 0; c < TOK / CHUNK; ++c) {
                k_gemm<<<dim3(2 * FFD / BN, CHUNK / BM), 256, 0, stream>>>(
                    X + (size_t)c * CHUNK * DIMD, w1, b1, Hb, CHUNK, 2 * FFD, DIMD);
                k_glu<<<dim3((CHUNK * FFD / 4) / 256), 256, 0, stream>>>(Hb, G);
                k_gemm<<<dim3(DIMD / BN, CHUNK / BM), 256, 0, stream>>>(
                    G, w2, b2, F + (size_t)c * CHUNK * DIMD, CHUNK, DIMD, FFD);
            }
            ++di;
        }
        // x = LN2(x + F)
        k_ln<<<TOK, 256, 0, stream>>>(X, F, ln2g + (size_t)l * DIMD, ln2b + (size_t)l * DIMD);
    }

    // classifier head
    k_rep<<<dim3((NB_ * DIMD + 255) / 256), 256, 0, stream>>>(X, REP);
    k_cls1<<<dim3(NB_ * DIMD / 4), 256, 0, stream>>>(REP, cW1, cB1, HCLS);
    k_cls2<<<dim3((NB_ * CCLS + 3) / 4), 256, 0, stream>>>(HCLS, cW2, cB2, out);
    k_writeaux<<<1, 1, 0, stream>>>(AUXP, out);
}

// Round 2
// 9177.911 us; speedup vs baseline: 2.3974x; 2.3974x over previous
//
#include <hip/hip_runtime.h>
#include <cstddef>

#define TOK   8192
#define DIMD  768
#define NH    12
#define DHD   64
#define SEQ   512
#define NB_   16
#define FFD   3072
#define NEXP  4
#define CCLS  10
#define CHUNK 2048

typedef short bf16x8 __attribute__((ext_vector_type(8)));
typedef float f32x4  __attribute__((ext_vector_type(4)));

// ---------------- workspace layout (float units) ----------------
static const size_t OFF_X    = 0;
static const size_t OFF_F    = OFF_X   + (size_t)TOK*DIMD;
static const size_t OFF_QKV  = OFF_F   + (size_t)TOK*DIMD;
static const size_t OFF_H    = OFF_QKV + (size_t)TOK*3*DIMD;
static const size_t OFF_G    = OFF_H   + (size_t)CHUNK*2*FFD;   // also attn-out: TOK*DIMD == CHUNK*FFD
static const size_t OFF_REP  = OFF_G   + (size_t)CHUNK*FFD;
static const size_t OFF_HCLS = OFF_REP + (size_t)NB_*DIMD;
static const size_t OFF_STAT = OFF_HCLS+ (size_t)NB_*DIMD;      // sums[4] + pad[4]
static const size_t OFF_INT  = OFF_STAT+ 8;                     // ints: cntA/B[4],cntE[4],offs[5],cursor[4]
static const size_t OFF_AUX  = OFF_INT + 24;                    // 1 float (NOT covered by per-layer memset)
static const size_t OFF_EID  = OFF_AUX + 1;                     // TOK ints
static const size_t OFF_PERM = OFF_EID + TOK;                   // TOK ints

__device__ __forceinline__ ushort f2bf(float f) {
    union { float f; unsigned u; } v; v.f = f;
    unsigned r = v.u + 0x7FFF + ((v.u >> 16) & 1);   // RNE
    return (ushort)(r >> 16);
}

// ---------------- embedding ----------------
__global__ __launch_bounds__(256) void k_embed(const int* __restrict__ ids,
                                               const float* __restrict__ te,
                                               const float* __restrict__ pe,
                                               float* __restrict__ x)
{
    int i = blockIdx.x * 256 + threadIdx.x;
    const int nd4 = DIMD / 4;
    if (i >= TOK * nd4) return;
    int t = i / nd4, d4 = i % nd4;
    int s = t % SEQ;
    int id = ids[t];
    float4 a = ((const float4*)(te + (size_t)id * DIMD))[d4];
    float4 b = ((const float4*)(pe + (size_t)s  * DIMD))[d4];
    float4 o; o.x = a.x + b.x; o.y = a.y + b.y; o.z = a.z + b.z; o.w = a.w + b.w;
    ((float4*)(x + (size_t)t * DIMD))[d4] = o;
}

// ---------------- bf16 MFMA GEMM: C[m,n] = sum_k A[m,k]*W[n,k] + bias[n] ----------------
// 128x128 tile, BK=32, 4 waves (2x2), each wave 64x64 via 4x4 frags of 16x16x32.
// fp32 inputs converted RNE->bf16 during reg-staged LDS fill. LDS row = 40 shorts
// (80 B: 16B-aligned for ds_read_b128, 2-way-max bank aliasing).
__global__ __launch_bounds__(256) void k_gemm(const float* __restrict__ A,
                                              const float* __restrict__ W,
                                              const float* __restrict__ bias,
                                              float* __restrict__ C,
                                              int M, int N, int K)
{
    __shared__ ushort As[128][40];
    __shared__ ushort Bs[128][40];
    const int tid = threadIdx.x;
    const int lane = tid & 63, wid = tid >> 6;
    const int wm = wid >> 1, wn = wid & 1;
    const int m0 = blockIdx.y * 128, n0 = blockIdx.x * 128;
    const int l15 = lane & 15, l4 = lane >> 4;
    const int strow = tid >> 3, stc = (tid & 7) * 4;
    f32x4 acc[4][4] = {};
    for (int k0 = 0; k0 < K; k0 += 32) {
        float4 av[4], bv[4];
#pragma unroll
        for (int it = 0; it < 4; ++it) {
            int r = it * 32 + strow;
            av[it] = *(const float4*)(A + (size_t)(m0 + r) * K + k0 + stc);
            bv[it] = *(const float4*)(W + (size_t)(n0 + r) * K + k0 + stc);
        }
        __syncthreads();
#pragma unroll
        for (int it = 0; it < 4; ++it) {
            int r = it * 32 + strow;
            ushort4 a4 = make_ushort4(f2bf(av[it].x), f2bf(av[it].y), f2bf(av[it].z), f2bf(av[it].w));
            ushort4 b4 = make_ushort4(f2bf(bv[it].x), f2bf(bv[it].y), f2bf(bv[it].z), f2bf(bv[it].w));
            *(ushort4*)&As[r][stc] = a4;
            *(ushort4*)&Bs[r][stc] = b4;
        }
        __syncthreads();
        bf16x8 af[4], bfr[4];
#pragma unroll
        for (int i = 0; i < 4; ++i) {
            af[i]  = *(const bf16x8*)&As[wm*64 + i*16 + l15][l4*8];
            bfr[i] = *(const bf16x8*)&Bs[wn*64 + i*16 + l15][l4*8];
        }
#pragma unroll
        for (int mi = 0; mi < 4; ++mi)
#pragma unroll
            for (int ni = 0; ni < 4; ++ni)
                acc[mi][ni] = __builtin_amdgcn_mfma_f32_16x16x32_bf16(af[mi], bfr[ni], acc[mi][ni], 0, 0, 0);
    }
#pragma unroll
    for (int ni = 0; ni < 4; ++ni) {
        int col = n0 + wn*64 + ni*16 + l15;
        float bb = bias[col];
#pragma unroll
        for (int mi = 0; mi < 4; ++mi) {
            int row = m0 + wm*64 + mi*16 + l4*4;
#pragma unroll
            for (int r = 0; r < 4; ++r)
                C[(size_t)(row + r) * N + col] = acc[mi][ni][r] + bb;
        }
    }
}

// ---------------- MoE gathered/scattered MFMA GEMM ----------------
__global__ __launch_bounds__(256) void k_gemm_moe(const float* __restrict__ A,
                                                  const float* __restrict__ W,
                                                  const float* __restrict__ bias,
                                                  float* __restrict__ C,
                                                  const int* __restrict__ perm,
                                                  const int* __restrict__ offsets,
                                                  int e, int chunk, int N, int K,
                                                  int gatherA, int Cld)
{
    __shared__ ushort As[128][40];
    __shared__ ushort Bs[128][40];
    __shared__ int    toks[128];
    const int base = offsets[e];
    const int cnt  = offsets[e + 1] - base;
    const int r0   = chunk * CHUNK + blockIdx.y * 128;   // row within this expert
    if (r0 >= cnt) return;
    const int tid = threadIdx.x;
    if (tid < 128) {
        int rg = r0 + tid;
        toks[tid] = perm[base + (rg < cnt ? rg : cnt - 1)];
    }
    __syncthreads();
    const int lane = tid & 63, wid = tid >> 6;
    const int wm = wid >> 1, wn = wid & 1;
    const int n0 = blockIdx.x * 128;
    const int lrow = blockIdx.y * 128;                   // chunk-local base row
    const int l15 = lane & 15, l4 = lane >> 4;
    const int strow = tid >> 3, stc = (tid & 7) * 4;
    f32x4 acc[4][4] = {};
    for (int k0 = 0; k0 < K; k0 += 32) {
        float4 av[4], bv[4];
#pragma unroll
        for (int it = 0; it < 4; ++it) {
            int r = it * 32 + strow;
            int arow = gatherA ? toks[r] : (lrow + r);
            av[it] = *(const float4*)(A + (size_t)arow * K + k0 + stc);
            bv[it] = *(const float4*)(W + (size_t)(n0 + r) * K + k0 + stc);
        }
        __syncthreads();
#pragma unroll
        for (int it = 0; it < 4; ++it) {
            int r = it * 32 + strow;
            ushort4 a4 = make_ushort4(f2bf(av[it].x), f2bf(av[it].y), f2bf(av[it].z), f2bf(av[it].w));
            ushort4 b4 = make_ushort4(f2bf(bv[it].x), f2bf(bv[it].y), f2bf(bv[it].z), f2bf(bv[it].w));
            *(ushort4*)&As[r][stc] = a4;
            *(ushort4*)&Bs[r][stc] = b4;
        }
        __syncthreads();
        bf16x8 af[4], bfr[4];
#pragma unroll
        for (int i = 0; i < 4; ++i) {
            af[i]  = *(const bf16x8*)&As[wm*64 + i*16 + l15][l4*8];
            bfr[i] = *(const bf16x8*)&Bs[wn*64 + i*16 + l15][l4*8];
        }
#pragma unroll
        for (int mi = 0; mi < 4; ++mi)
#pragma unroll
            for (int ni = 0; ni < 4; ++ni)
                acc[mi][ni] = __builtin_amdgcn_mfma_f32_16x16x32_bf16(af[mi], bfr[ni], acc[mi][ni], 0, 0, 0);
    }
#pragma unroll
    for (int ni = 0; ni < 4; ++ni) {
        int col = n0 + wn*64 + ni*16 + l15;
        float bb = bias[col];
#pragma unroll
        for (int mi = 0; mi < 4; ++mi) {
            int rowi = wm*64 + mi*16 + l4*4;
#pragma unroll
            for (int r = 0; r < 4; ++r) {
                float o = acc[mi][ni][r] + bb;
                int ri = rowi + r;
                if (gatherA) {
                    C[(size_t)(lrow + ri) * N + col] = o;          // linear into h chunk
                } else {
                    if (r0 + ri < cnt)
                        C[(size_t)toks[ri] * Cld + col] = o;       // scatter to f[token]
                }
            }
        }
    }
}

// ---------------- GLU: g = a * silu(b), [a,b] = split(h) ----------------
__global__ __launch_bounds__(256) void k_glu(const float* __restrict__ h, float* __restrict__ g)
{
    int i = blockIdx.x * 256 + threadIdx.x;             // float4 index over CHUNK*FFD
    const int nf4 = FFD / 4;
    if (i >= CHUNK * nf4) return;
    int r = i / nf4, j4 = i % nf4;
    float4 a = ((const float4*)(h + (size_t)r * 2 * FFD))[j4];
    float4 b = ((const float4*)(h + (size_t)r * 2 * FFD + FFD))[j4];
    float4 o;
    o.x = a.x * (b.x / (1.f + __expf(-b.x)));
    o.y = a.y * (b.y / (1.f + __expf(-b.y)));
    o.z = a.z * (b.z / (1.f + __expf(-b.z)));
    o.w = a.w * (b.w / (1.f + __expf(-b.w)));
    ((float4*)g)[i] = o;
}

// ---------------- attention (flash-style, one thread per q-row) ----------------
__global__ __launch_bounds__(128) void k_attn(const float* __restrict__ qkv, float* __restrict__ out)
{
    const int bh = blockIdx.x;
    const int b = bh / NH, h = bh % NH;
    const int qrow = blockIdx.y * 128 + threadIdx.x;    // 0..511
    const int t = b * SEQ + qrow;
    const float* qp = qkv + (size_t)t * 3 * DIMD + h * DHD;
    float q[DHD], o[DHD];
#pragma unroll
    for (int d = 0; d < DHD; d += 4) {
        float4 v = *(const float4*)(qp + d);
        q[d] = v.x; q[d+1] = v.y; q[d+2] = v.z; q[d+3] = v.w;
        o[d] = 0.f; o[d+1] = 0.f; o[d+2] = 0.f; o[d+3] = 0.f;
    }
    float m = -3.0e38f, l = 0.f;
    __shared__ float Ks[32][DHD];
    __shared__ float Vs[32][DHD];
    for (int kt = 0; kt < SEQ; kt += 32) {
        __syncthreads();
        for (int idx = threadIdx.x; idx < 32 * (DHD/4); idx += 128) {
            int kk = idx / (DHD/4), d4 = idx % (DHD/4);
            int t2 = b * SEQ + kt + kk;
            const float* kp = qkv + (size_t)t2 * 3 * DIMD + DIMD + h * DHD;
            ((float4*)Ks[kk])[d4] = ((const float4*)kp)[d4];
            ((float4*)Vs[kk])[d4] = ((const float4*)(kp + DIMD))[d4];
        }
        __syncthreads();
        for (int kk = 0; kk < 32; ++kk) {
            float s0=0.f, s1=0.f, s2=0.f, s3=0.f;
#pragma unroll
            for (int d = 0; d < DHD; d += 4) {
                s0 += q[d+0] * Ks[kk][d+0];
                s1 += q[d+1] * Ks[kk][d+1];
                s2 += q[d+2] * Ks[kk][d+2];
                s3 += q[d+3] * Ks[kk][d+3];
            }
            float sv = (s0 + s1 + s2 + s3) * 0.125f;
            float nm = fmaxf(m, sv);
            float c = __expf(m - nm);
            float p = __expf(sv - nm);
            l = l * c + p;
#pragma unroll
            for (int d = 0; d < DHD; ++d) o[d] = o[d] * c + p * Vs[kk][d];
            m = nm;
        }
    }
    float inv = 1.f / l;
    float* op = out + (size_t)t * DIMD + h * DHD;
#pragma unroll
    for (int d = 0; d < DHD; d += 4) {
        float4 v; v.x = o[d]*inv; v.y = o[d+1]*inv; v.z = o[d+2]*inv; v.w = o[d+3]*inv;
        *(float4*)(op + d) = v;
    }
}

// ---------------- fused residual + LayerNorm: x = LN(x + f)*g + b ----------------
__global__ __launch_bounds__(256) void k_ln(float* __restrict__ x, const float* __restrict__ f,
                                            const float* __restrict__ g, const float* __restrict__ b)
{
    const int t = blockIdx.x, tid = threadIdx.x;
    __shared__ float y[DIMD];
    __shared__ float red[256];
    float* xr = x + (size_t)t * DIMD;
    const float* fr = f + (size_t)t * DIMD;
    float s = 0.f;
    for (int d = tid; d < DIMD; d += 256) { float v = xr[d] + fr[d]; y[d] = v; s += v; }
    red[tid] = s; __syncthreads();
    for (int off = 128; off > 0; off >>= 1) { if (tid < off) red[tid] += red[tid + off]; __syncthreads(); }
    const float mean = red[0] * (1.f / DIMD);
    __syncthreads();
    s = 0.f;
    for (int d = tid; d < DIMD; d += 256) { float v = y[d] - mean; s += v * v; }
    red[tid] = s; __syncthreads();
    for (int off = 128; off > 0; off >>= 1) { if (tid < off) red[tid] += red[tid + off]; __syncthreads(); }
    const float rstd = 1.f / sqrtf(red[0] * (1.f / DIMD) + 1e-5f);
    for (int d = tid; d < DIMD; d += 256) xr[d] = (y[d] - mean) * rstd * g[d] + b[d];
}

// ---------------- MoE gating: 64 blocks x 4 waves, 32 tokens/wave ----------------
// Weights preloaded to registers; butterfly shfl reduce; block-level partial sums;
// 12 atomics per block (was 12 per token -> 703us of same-address atomic serialization).
__global__ __launch_bounds__(256) void k_gate(const float* __restrict__ x,
                                              const float* __restrict__ gAw, const float* __restrict__ gAb,
                                              const float* __restrict__ gBw, const float* __restrict__ gBb,
                                              float* __restrict__ sums, int* __restrict__ cnts,
                                              int* __restrict__ e_id)
{
    const int tid = threadIdx.x, lane = tid & 63, wid = tid >> 6;
    const int gw = blockIdx.x * 4 + wid;                 // 0..255
    float wA0[12], wA1[12], wB0[12], wB1[12];
#pragma unroll
    for (int i = 0; i < 12; ++i) {
        int d = lane + i * 64;
        wA0[i] = gAw[d]; wA1[i] = gAw[DIMD + d];
        wB0[i] = gBw[d]; wB1[i] = gBw[DIMD + d];
    }
    const float bA0 = gAb[0], bA1 = gAb[1], bB0 = gBb[0], bB1 = gBb[1];
    float sA0 = 0.f, sA1 = 0.f, sB0 = 0.f, sB1 = 0.f;
    int cA1 = 0, cB1 = 0, cE0 = 0, cE1 = 0, cE2 = 0;
    for (int i = 0; i < 32; ++i) {
        int t = gw * 32 + i;
        const float* xr = x + (size_t)t * DIMD;
        float a0 = 0.f, a1 = 0.f, b0 = 0.f, b1 = 0.f;
#pragma unroll
        for (int j = 0; j < 12; ++j) {
            float v = xr[lane + j * 64];
            a0 = fmaf(v, wA0[j], a0); a1 = fmaf(v, wA1[j], a1);
            b0 = fmaf(v, wB0[j], b0); b1 = fmaf(v, wB1[j], b1);
        }
#pragma unroll
        for (int off = 1; off < 64; off <<= 1) {
            a0 += __shfl_xor(a0, off); a1 += __shfl_xor(a1, off);
            b0 += __shfl_xor(b0, off); b1 += __shfl_xor(b1, off);
        }
        a0 += bA0; a1 += bA1; b0 += bB0; b1 += bB1;
        int iA = (a1 > a0) ? 1 : 0;
        int iB = (b1 > b0) ? 1 : 0;
        float mA = fmaxf(a0, a1); float eA0 = __expf(a0 - mA), eA1 = __expf(a1 - mA);
        float dA = 1.f / (eA0 + eA1);
        float mB = fmaxf(b0, b1); float eB0 = __expf(b0 - mB), eB1 = __expf(b1 - mB);
        float dB = 1.f / (eB0 + eB1);
        sA0 += eA0 * dA; sA1 += eA1 * dA;
        sB0 += eB0 * dB; sB1 += eB1 * dB;
        cA1 += iA; cB1 += iB;
        int e = iA * 2 + iB;
        cE0 += (e == 0); cE1 += (e == 1); cE2 += (e == 2);
        if (lane == 0) e_id[t] = e;
    }
    __shared__ float fpart[4][4];
    __shared__ int   ipart[4][8];
    if (lane == 0) {
        fpart[wid][0] = sA0; fpart[wid][1] = sA1; fpart[wid][2] = sB0; fpart[wid][3] = sB1;
        ipart[wid][0] = 32 - cA1; ipart[wid][1] = cA1;
        ipart[wid][2] = 32 - cB1; ipart[wid][3] = cB1;
        ipart[wid][4] = cE0; ipart[wid][5] = cE1; ipart[wid][6] = cE2;
        ipart[wid][7] = 32 - cE0 - cE1 - cE2;
    }
    __syncthreads();
    if (tid < 4)  atomicAdd(sums + tid, fpart[0][tid] + fpart[1][tid] + fpart[2][tid] + fpart[3][tid]);
    else if (tid >= 64 && tid < 72) {
        int k = tid - 64;
        atomicAdd(cnts + k, ipart[0][k] + ipart[1][k] + ipart[2][k] + ipart[3][k]);
    }
}

__global__ void k_offsets(const int* __restrict__ cntE, int* __restrict__ offs, int* __restrict__ cursor)
{
    if (threadIdx.x == 0) {
        int a = 0;
        for (int e = 0; e < NEXP; ++e) { offs[e] = a; a += cntE[e]; cursor[e] = 0; }
        offs[NEXP] = a;
    }
}

// wave-aggregated scatter: 4 atomics per wave instead of 1 per thread
__global__ __launch_bounds__(256) void k_scatter(const int* __restrict__ e_id, const int* __restrict__ offs,
                                                 int* __restrict__ cursor, int* __restrict__ perm)
{
    int t = blockIdx.x * 256 + threadIdx.x;
    int lane = threadIdx.x & 63;
    int e = e_id[t];
#pragma unroll
    for (int eo = 0; eo < NEXP; ++eo) {
        unsigned long long m = __ballot(e == eo);
        if (m == 0ULL) continue;
        int leader = __ffsll((long long)m) - 1;
        int base = 0;
        if (lane == leader) base = atomicAdd(cursor + eo, (int)__popcll(m));
        base = __shfl(base, leader);
        if (e == eo) {
            int lower = (int)__popcll(m & ((1ULL << lane) - 1ULL));
            perm[offs[eo] + base + lower] = t;
        }
    }
}

__global__ void k_aux(const float* __restrict__ sums, const int* __restrict__ cnts, float* __restrict__ aux_acc)
{
    if (threadIdx.x == 0) {
        const float invT2 = 1.f / ((float)TOK * (float)TOK);
        float aA = 2.f * (sums[0] * (float)cnts[0] + sums[1] * (float)cnts[1]) * invT2;
        float aB = 2.f * (sums[2] * (float)cnts[2] + sums[3] * (float)cnts[3]) * invT2;
        *aux_acc += aA + aB;
    }
}

// ---------------- classifier head ----------------
__global__ __launch_bounds__(256) void k_rep(const float* __restrict__ x, float* __restrict__ rep)
{
    int i = blockIdx.x * 256 + threadIdx.x;
    if (i >= NB_ * DIMD) return;
    int b = i / DIMD, d = i % DIMD;
    float s = 0.f;
    for (int q = 0; q < SEQ; ++q) s += x[((size_t)b * SEQ + q) * DIMD + d];
    rep[i] = s * (1.f / SEQ);
}

__global__ __launch_bounds__(256) void k_cls1(const float* __restrict__ rep, const float* __restrict__ cW1,
                                              const float* __restrict__ cB1, float* __restrict__ hcls)
{
    int w = blockIdx.x * 4 + (threadIdx.x >> 6);
    int lane = threadIdx.x & 63;
    if (w >= NB_ * DIMD) return;
    int b = w / DIMD, i = w % DIMD;
    float s = 0.f;
    for (int d = lane; d < DIMD; d += 64) s += rep[b * DIMD + d] * cW1[(size_t)i * DIMD + d];
    for (int off = 32; off > 0; off >>= 1) s += __shfl_down(s, off);
    if (lane == 0) hcls[w] = fmaxf(s + cB1[i], 0.f);
}

__global__ __launch_bounds__(256) void k_cls2(const float* __restrict__ hcls, const float* __restrict__ cW2,
                                              const float* __restrict__ cB2, float* __restrict__ out)
{
    int w = blockIdx.x * 4 + (threadIdx.x >> 6);
    int lane = threadIdx.x & 63;
    if (w >= NB_ * CCLS) return;
    int b = w / CCLS, c = w % CCLS;
    float s = 0.f;
    for (int d = lane; d < DIMD; d += 64) s += hcls[b * DIMD + d] * cW2[(size_t)c * DIMD + d];
    for (int off = 32; off > 0; off >>= 1) s += __shfl_down(s, off);
    if (lane == 0) out[w] = s + cB2[c];
}

__global__ void k_writeaux(const float* __restrict__ aux_acc, float* __restrict__ out)
{
    if (threadIdx.x == 0) out[NB_ * CCLS] = *aux_acc;
}

// ---------------- host launch ----------------
extern "C" void kernel_launch(void* const* d_in, const int* in_sizes, int n_in,
                              void* d_out, int out_size, void* d_ws, size_t ws_size,
                              hipStream_t stream)
{
    const int*   input_ids = (const int*)  d_in[0];
    const float* tok_emb   = (const float*)d_in[1];
    const float* pos_emb   = (const float*)d_in[2];
    const float* wqkv      = (const float*)d_in[3];
    const float* bqkv      = (const float*)d_in[4];
    const float* wo        = (const float*)d_in[5];
    const float* bo        = (const float*)d_in[6];
    const float* ln1g      = (const float*)d_in[7];
    const float* ln1b      = (const float*)d_in[8];
    const float* ln2g      = (const float*)d_in[9];
    const float* ln2b      = (const float*)d_in[10];
    const float* dW1       = (const float*)d_in[11];
    const float* dB1       = (const float*)d_in[12];
    const float* dW2       = (const float*)d_in[13];
    const float* dB2       = (const float*)d_in[14];
    const float* mW1       = (const float*)d_in[15];
    const float* mB1       = (const float*)d_in[16];
    const float* mW2       = (const float*)d_in[17];
    const float* mB2       = (const float*)d_in[18];
    const float* gAw       = (const float*)d_in[19];
    const float* gAb       = (const float*)d_in[20];
    const float* gBw       = (const float*)d_in[21];
    const float* gBb       = (const float*)d_in[22];
    const float* cW1       = (const float*)d_in[23];
    const float* cB1       = (const float*)d_in[24];
    const float* cW2       = (const float*)d_in[25];
    const float* cB2       = (const float*)d_in[26];

    float* out = (float*)d_out;
    float* ws  = (float*)d_ws;

    float* X    = ws + OFF_X;
    float* F    = ws + OFF_F;
    float* QKV  = ws + OFF_QKV;
    float* Hb   = ws + OFF_H;
    float* G    = ws + OFF_G;     // attn-out and GLU-out (time-shared)
    float* REP  = ws + OFF_REP;
    float* HCLS = ws + OFF_HCLS;
    float* SUMS = ws + OFF_STAT;
    int*   CNTS = (int*)(ws + OFF_INT);       // [0..3] cntA/cntB, [4..7] cntE
    int*   OFFS = CNTS + 8;                   // 5 ints
    int*   CURS = CNTS + 13;                  // 4 ints
    float* AUXP = ws + OFF_AUX;
    int*   EID  = (int*)(ws + OFF_EID);
    int*   PERM = (int*)(ws + OFF_PERM);

    hipMemsetAsync(AUXP, 0, sizeof(float), stream);

    k_embed<<<dim3((TOK * DIMD / 4) / 256), 256, 0, stream>>>(input_ids, tok_emb, pos_emb, X);

    int di = 0, mi = 0;
    for (int l = 0; l < 6; ++l) {
        // QKV projection
        k_gemm<<<dim3(3 * DIMD / 128, TOK / 128), 256, 0, stream>>>(
            X, wqkv + (size_t)l * 3 * DIMD * DIMD, bqkv + (size_t)l * 3 * DIMD, QKV, TOK, 3 * DIMD, DIMD);
        // attention -> G
        k_attn<<<dim3(NB_ * NH, SEQ / 128), 128, 0, stream>>>(QKV, G);
        // output projection -> F
        k_gemm<<<dim3(DIMD / 128, TOK / 128), 256, 0, stream>>>(
            G, wo + (size_t)l * DIMD * DIMD, bo + (size_t)l * DIMD, F, TOK, DIMD, DIMD);
        // x = LN1(x + F)
        k_ln<<<TOK, 256, 0, stream>>>(X, F, ln1g + (size_t)l * DIMD, ln1b + (size_t)l * DIMD);

        if (l == 1 || l == 3 || l == 5) {
            // ---- MoE ----
            hipMemsetAsync(SUMS, 0, (8 + 24) * sizeof(float), stream);   // sums + int region (not aux)
            k_gate<<<64, 256, 0, stream>>>(X,
                gAw + (size_t)mi * 2 * DIMD, gAb + (size_t)mi * 2,
                gBw + (size_t)mi * 2 * DIMD, gBb + (size_t)mi * 2,
                SUMS, CNTS, EID);
            k_offsets<<<1, 1, 0, stream>>>(CNTS + 4, OFFS, CURS);
            k_scatter<<<TOK / 256, 256, 0, stream>>>(EID, OFFS, CURS, PERM);
            for (int e = 0; e < NEXP; ++e) {
                const float* w1 = mW1 + ((size_t)mi * NEXP + e) * 2 * FFD * DIMD;
                const float* b1 = mB1 + ((size_t)mi * NEXP + e) * 2 * FFD;
                const float* w2 = mW2 + ((size_t)mi * NEXP + e) * (size_t)DIMD * FFD;
                const float* b2 = mB2 + ((size_t)mi * NEXP + e) * DIMD;
                for (int c = 0; c < TOK / CHUNK; ++c) {
                    k_gemm_moe<<<dim3(2 * FFD / 128, CHUNK / 128), 256, 0, stream>>>(
                        X, w1, b1, Hb, PERM, OFFS, e, c, 2 * FFD, DIMD, 1, 2 * FFD);
                    k_glu<<<dim3((CHUNK * FFD / 4) / 256), 256, 0, stream>>>(Hb, G);
                    k_gemm_moe<<<dim3(DIMD / 128, CHUNK / 128), 256, 0, stream>>>(
                        G, w2, b2, F, PERM, OFFS, e, c, DIMD, FFD, 0, DIMD);
                }
            }
            k_aux<<<1, 1, 0, stream>>>(SUMS, CNTS, AUXP);
            ++mi;
        } else {
            // ---- dense FFN (chunked over tokens) ----
            const float* w1 = dW1 + (size_t)di * 2 * FFD * DIMD;
            const float* b1 = dB1 + (size_t)di * 2 * FFD;
            const float* w2 = dW2 + (size_t)di * (size_t)DIMD * FFD;
            const float* b2 = dB2 + (size_t)di * DIMD;
            for (int c = 0; c < TOK / CHUNK; ++c) {
                k_gemm<<<dim3(2 * FFD / 128, CHUNK / 128), 256, 0, stream>>>(
                    X + (size_t)c * CHUNK * DIMD, w1, b1, Hb, CHUNK, 2 * FFD, DIMD);
                k_glu<<<dim3((CHUNK * FFD / 4) / 256), 256, 0, stream>>>(Hb, G);
                k_gemm<<<dim3(DIMD / 128, CHUNK / 128), 256, 0, stream>>>(
                    G, w2, b2, F + (size_t)c * CHUNK * DIMD, CHUNK, DIMD, FFD);
            }
            ++di;
        }
        // x = LN2(x + F)
        k_ln<<<TOK, 256, 0, stream>>>(X, F, ln2g + (size_t)l * DIMD, ln2b + (size_t)l * DIMD);
    }

    // classifier head
    k_rep<<<dim3((NB_ * DIMD + 255) / 256), 256, 0, stream>>>(X, REP);
    k_cls1<<<dim3(NB_ * DIMD / 4), 256, 0, stream>>>(REP, cW1, cB1, HCLS);
    k_cls2<<<dim3((NB_ * CCLS + 3) / 4), 256, 0, stream>>>(HCLS, cW2, cB2, out);
    k_writeaux<<<1, 1, 0, stream>>>(AUXP, out);
}

// Round 3
// 7499.688 us; speedup vs baseline: 2.9339x; 1.2238x over previous
//
#include <hip/hip_runtime.h>
#include <cstddef>

#define TOK   8192
#define DIMD  768
#define NH    12
#define DHD   64
#define SEQ   512
#define NB_   16
#define FFD   3072
#define NEXP  4
#define CCLS  10
#define CHUNK 2048

typedef short bf16x8 __attribute__((ext_vector_type(8)));
typedef float f32x4  __attribute__((ext_vector_type(4)));

// ---------------- workspace layout (float units) ----------------
static const size_t OFF_X    = 0;
static const size_t OFF_F    = OFF_X   + (size_t)TOK*DIMD;
static const size_t OFF_QKV  = OFF_F   + (size_t)TOK*DIMD;      // bf16 now (uses half)
static const size_t OFF_H    = OFF_QKV + (size_t)TOK*3*DIMD;    // bf16 h
static const size_t OFF_G    = OFF_H   + (size_t)CHUNK*2*FFD;   // bf16: attn-out / glu-out
static const size_t OFF_REP  = OFF_G   + (size_t)CHUNK*FFD;
static const size_t OFF_HCLS = OFF_REP + (size_t)NB_*DIMD;
static const size_t OFF_STAT = OFF_HCLS+ (size_t)NB_*DIMD;      // sums[4] + pad[4]
static const size_t OFF_INT  = OFF_STAT+ 8;                     // ints
static const size_t OFF_AUX  = OFF_INT + 24;                    // 1 float
static const size_t OFF_EID  = OFF_AUX + 1;                     // TOK ints
static const size_t OFF_PERM = OFF_EID + TOK;                   // TOK ints

__device__ __forceinline__ ushort f2bf(float f) {
    union { float f; unsigned u; } v; v.f = f;
    unsigned r = v.u + 0x7FFF + ((v.u >> 16) & 1);   // RNE
    return (ushort)(r >> 16);
}
__device__ __forceinline__ float bf2f(ushort u) {
    union { unsigned u; float f; } v; v.u = ((unsigned)u) << 16;
    return v.f;
}

// ---------------- embedding ----------------
__global__ __launch_bounds__(256) void k_embed(const int* __restrict__ ids,
                                               const float* __restrict__ te,
                                               const float* __restrict__ pe,
                                               float* __restrict__ x)
{
    int i = blockIdx.x * 256 + threadIdx.x;
    const int nd4 = DIMD / 4;
    if (i >= TOK * nd4) return;
    int t = i / nd4, d4 = i % nd4;
    int s = t % SEQ;
    int id = ids[t];
    float4 a = ((const float4*)(te + (size_t)id * DIMD))[d4];
    float4 b = ((const float4*)(pe + (size_t)s  * DIMD))[d4];
    float4 o; o.x = a.x + b.x; o.y = a.y + b.y; o.z = a.z + b.z; o.w = a.w + b.w;
    ((float4*)(x + (size_t)t * DIMD))[d4] = o;
}

// ---------------- bf16 MFMA GEMM: C[m,n] = sum_k A[m,k]*W[n,k] + bias[n] ----------------
// ABF: A is bf16 (ushort, ld=K) else fp32 (convert during staging).
// CBF: C written bf16 else fp32.
template<int ABF, int CBF>
__global__ __launch_bounds__(256) void k_gemm_t(const void* __restrict__ A_,
                                                const float* __restrict__ W,
                                                const float* __restrict__ bias,
                                                void* __restrict__ C_,
                                                int M, int N, int K)
{
    __shared__ ushort As[128][40];
    __shared__ ushort Bs[128][40];
    const int tid = threadIdx.x;
    const int lane = tid & 63, wid = tid >> 6;
    const int wm = wid >> 1, wn = wid & 1;
    const int m0 = blockIdx.y * 128, n0 = blockIdx.x * 128;
    const int l15 = lane & 15, l4 = lane >> 4;
    const int strow = tid >> 3, stc = (tid & 7) * 4;
    const int srow = tid >> 2, sc8 = (tid & 3) * 8;
    f32x4 acc[4][4] = {};
    for (int k0 = 0; k0 < K; k0 += 32) {
        float4 bv[4];
        float4 av[4];
        uint4  av8[2];
#pragma unroll
        for (int it = 0; it < 4; ++it)
            bv[it] = *(const float4*)(W + (size_t)(n0 + it * 32 + strow) * K + k0 + stc);
        if constexpr (ABF) {
            const ushort* A = (const ushort*)A_;
#pragma unroll
            for (int it = 0; it < 2; ++it)
                av8[it] = *(const uint4*)(A + (size_t)(m0 + it * 64 + srow) * K + k0 + sc8);
        } else {
            const float* A = (const float*)A_;
#pragma unroll
            for (int it = 0; it < 4; ++it)
                av[it] = *(const float4*)(A + (size_t)(m0 + it * 32 + strow) * K + k0 + stc);
        }
        __syncthreads();
#pragma unroll
        for (int it = 0; it < 4; ++it) {
            int r = it * 32 + strow;
            float4 w4 = bv[it];
            *(ushort4*)&Bs[r][stc] = make_ushort4(f2bf(w4.x), f2bf(w4.y), f2bf(w4.z), f2bf(w4.w));
        }
        if constexpr (ABF) {
#pragma unroll
            for (int it = 0; it < 2; ++it)
                *(uint4*)&As[it * 64 + srow][sc8] = av8[it];
        } else {
#pragma unroll
            for (int it = 0; it < 4; ++it) {
                int r = it * 32 + strow;
                float4 a4 = av[it];
                *(ushort4*)&As[r][stc] = make_ushort4(f2bf(a4.x), f2bf(a4.y), f2bf(a4.z), f2bf(a4.w));
            }
        }
        __syncthreads();
        bf16x8 af[4], bfr[4];
#pragma unroll
        for (int i = 0; i < 4; ++i) {
            af[i]  = *(const bf16x8*)&As[wm*64 + i*16 + l15][l4*8];
            bfr[i] = *(const bf16x8*)&Bs[wn*64 + i*16 + l15][l4*8];
        }
#pragma unroll
        for (int mi = 0; mi < 4; ++mi)
#pragma unroll
            for (int ni = 0; ni < 4; ++ni)
                acc[mi][ni] = __builtin_amdgcn_mfma_f32_16x16x32_bf16(af[mi], bfr[ni], acc[mi][ni], 0, 0, 0);
    }
#pragma unroll
    for (int ni = 0; ni < 4; ++ni) {
        int col = n0 + wn*64 + ni*16 + l15;
        float bb = bias[col];
#pragma unroll
        for (int mi = 0; mi < 4; ++mi) {
            int row = m0 + wm*64 + mi*16 + l4*4;
#pragma unroll
            for (int r = 0; r < 4; ++r) {
                float o = acc[mi][ni][r] + bb;
                if constexpr (CBF) ((ushort*)C_)[(size_t)(row + r) * N + col] = f2bf(o);
                else               ((float*)C_)[(size_t)(row + r) * N + col] = o;
            }
        }
    }
}

// ---------------- MoE gathered/scattered MFMA GEMM ----------------
// GA=1: A rows gathered via perm (fp32 X), C linear bf16 h-chunk.
// GA=0: A rows linear bf16 g-chunk, C scattered fp32 to f[token] (ld=Cld).
template<int GA, int ABF, int CBF>
__global__ __launch_bounds__(256) void k_moe_t(const void* __restrict__ A_,
                                               const float* __restrict__ W,
                                               const float* __restrict__ bias,
                                               void* __restrict__ C_,
                                               const int* __restrict__ perm,
                                               const int* __restrict__ offsets,
                                               int e, int chunk, int N, int K, int Cld)
{
    __shared__ ushort As[128][40];
    __shared__ ushort Bs[128][40];
    __shared__ int    toks[128];
    const int base = offsets[e];
    const int cnt  = offsets[e + 1] - base;
    const int r0   = chunk * CHUNK + blockIdx.y * 128;
    if (r0 >= cnt) return;
    const int tid = threadIdx.x;
    if (tid < 128) {
        int rg = r0 + tid;
        toks[tid] = perm[base + (rg < cnt ? rg : cnt - 1)];
    }
    __syncthreads();
    const int lane = tid & 63, wid = tid >> 6;
    const int wm = wid >> 1, wn = wid & 1;
    const int n0 = blockIdx.x * 128;
    const int lrow = blockIdx.y * 128;
    const int l15 = lane & 15, l4 = lane >> 4;
    const int strow = tid >> 3, stc = (tid & 7) * 4;
    const int srow = tid >> 2, sc8 = (tid & 3) * 8;
    f32x4 acc[4][4] = {};
    for (int k0 = 0; k0 < K; k0 += 32) {
        float4 bv[4];
        float4 av[4];
        uint4  av8[2];
#pragma unroll
        for (int it = 0; it < 4; ++it)
            bv[it] = *(const float4*)(W + (size_t)(n0 + it * 32 + strow) * K + k0 + stc);
        if constexpr (ABF) {
            const ushort* A = (const ushort*)A_;
#pragma unroll
            for (int it = 0; it < 2; ++it)
                av8[it] = *(const uint4*)(A + (size_t)(lrow + it * 64 + srow) * K + k0 + sc8);
        } else {
            const float* A = (const float*)A_;
#pragma unroll
            for (int it = 0; it < 4; ++it) {
                int arow = GA ? toks[it * 32 + strow] : (lrow + it * 32 + strow);
                av[it] = *(const float4*)(A + (size_t)arow * K + k0 + stc);
            }
        }
        __syncthreads();
#pragma unroll
        for (int it = 0; it < 4; ++it) {
            int r = it * 32 + strow;
            float4 w4 = bv[it];
            *(ushort4*)&Bs[r][stc] = make_ushort4(f2bf(w4.x), f2bf(w4.y), f2bf(w4.z), f2bf(w4.w));
        }
        if constexpr (ABF) {
#pragma unroll
            for (int it = 0; it < 2; ++it)
                *(uint4*)&As[it * 64 + srow][sc8] = av8[it];
        } else {
#pragma unroll
            for (int it = 0; it < 4; ++it) {
                int r = it * 32 + strow;
                float4 a4 = av[it];
                *(ushort4*)&As[r][stc] = make_ushort4(f2bf(a4.x), f2bf(a4.y), f2bf(a4.z), f2bf(a4.w));
            }
        }
        __syncthreads();
        bf16x8 af[4], bfr[4];
#pragma unroll
        for (int i = 0; i < 4; ++i) {
            af[i]  = *(const bf16x8*)&As[wm*64 + i*16 + l15][l4*8];
            bfr[i] = *(const bf16x8*)&Bs[wn*64 + i*16 + l15][l4*8];
        }
#pragma unroll
        for (int mi = 0; mi < 4; ++mi)
#pragma unroll
            for (int ni = 0; ni < 4; ++ni)
                acc[mi][ni] = __builtin_amdgcn_mfma_f32_16x16x32_bf16(af[mi], bfr[ni], acc[mi][ni], 0, 0, 0);
    }
#pragma unroll
    for (int ni = 0; ni < 4; ++ni) {
        int col = n0 + wn*64 + ni*16 + l15;
        float bb = bias[col];
#pragma unroll
        for (int mi = 0; mi < 4; ++mi) {
            int rowi = wm*64 + mi*16 + l4*4;
#pragma unroll
            for (int r = 0; r < 4; ++r) {
                float o = acc[mi][ni][r] + bb;
                int ri = rowi + r;
                if constexpr (CBF) {
                    ((ushort*)C_)[(size_t)(lrow + ri) * N + col] = f2bf(o);
                } else {
                    if (r0 + ri < cnt)
                        ((float*)C_)[(size_t)toks[ri] * Cld + col] = o;
                }
            }
        }
    }
}

// ---------------- GLU (bf16 in/out): g = a * silu(b) ----------------
__global__ __launch_bounds__(256) void k_glu(const ushort* __restrict__ h, ushort* __restrict__ g)
{
    int i = blockIdx.x * 256 + threadIdx.x;             // ushort8 chunk over CHUNK*FFD
    const int nf8 = FFD / 8;
    if (i >= CHUNK * nf8) return;
    int r = i / nf8, j8 = i % nf8;
    uint4 a8 = *(const uint4*)(h + (size_t)r * 2 * FFD + j8 * 8);
    uint4 b8 = *(const uint4*)(h + (size_t)r * 2 * FFD + FFD + j8 * 8);
    const ushort* ap = (const ushort*)&a8;
    const ushort* bp = (const ushort*)&b8;
    ushort res[8];
#pragma unroll
    for (int j = 0; j < 8; ++j) {
        float a = bf2f(ap[j]), b = bf2f(bp[j]);
        res[j] = f2bf(a * (b / (1.f + __expf(-b))));
    }
    *(uint4*)(g + (size_t)i * 8) = *(uint4*)res;
}

// ---------------- MFMA flash attention ----------------
// Block: one (b,h) x 64 q-rows, 4 waves x 16 q-rows. QKV bf16 [t][2304].
// S = Q@K^T (col=key=l15, row=q=l4*4+r), wave-local online softmax,
// P transposed via per-wave LDS into A-frag layout, V staged transposed.
__global__ __launch_bounds__(256) void k_attn(const ushort* __restrict__ qkv, ushort* __restrict__ out)
{
    __shared__ ushort Qs[64][72];
    __shared__ ushort Ks[64][72];
    __shared__ ushort Vt[64][72];
    __shared__ ushort Ps[4][16][72];
    const int bh = blockIdx.x;
    const int b = bh / NH, h = bh % NH;
    const int qt = blockIdx.y;
    const int tid = threadIdx.x, lane = tid & 63, w = tid >> 6;
    const int l15 = lane & 15, l4 = lane >> 4;
    const int t0 = b * SEQ + qt * 64;
    {
        int r = tid >> 3, c8 = (tid & 7) * 8;
#pragma unroll
        for (int p = 0; p < 2; ++p) {
            int rr = r + p * 32;
            *(uint4*)&Qs[rr][c8] = *(const uint4*)(qkv + (size_t)(t0 + rr) * 3 * DIMD + h * DHD + c8);
        }
    }
    __syncthreads();
    bf16x8 aq[2];
    aq[0] = *(const bf16x8*)&Qs[w*16 + l15][l4*8];
    aq[1] = *(const bf16x8*)&Qs[w*16 + l15][32 + l4*8];
    f32x4 o[4] = {};
    float m[4], lsum[4];
#pragma unroll
    for (int r = 0; r < 4; ++r) { m[r] = -3.0e38f; lsum[r] = 0.f; }
    for (int kt = 0; kt < SEQ; kt += 64) {
        __syncthreads();
        {
            int r = tid >> 3, c8 = (tid & 7) * 8;
#pragma unroll
            for (int p = 0; p < 2; ++p) {
                int rr = r + p * 32;
                const ushort* kp = qkv + (size_t)(b * SEQ + kt + rr) * 3 * DIMD + DIMD + h * DHD;
                *(uint4*)&Ks[rr][c8] = *(const uint4*)(kp + c8);
                uint4 vv = *(const uint4*)(kp + DIMD + c8);
                const ushort* vs = (const ushort*)&vv;
#pragma unroll
                for (int j = 0; j < 8; ++j) Vt[c8 + j][rr] = vs[j];
            }
        }
        __syncthreads();
        f32x4 s[4] = {};
#pragma unroll
        for (int kk = 0; kk < 2; ++kk)
#pragma unroll
            for (int ni = 0; ni < 4; ++ni) {
                bf16x8 bk = *(const bf16x8*)&Ks[ni*16 + l15][kk*32 + l4*8];
                s[ni] = __builtin_amdgcn_mfma_f32_16x16x32_bf16(aq[kk], bk, s[ni], 0, 0, 0);
            }
        float csc[4];
#pragma unroll
        for (int r = 0; r < 4; ++r) {
            float mx = -3.0e38f;
#pragma unroll
            for (int ni = 0; ni < 4; ++ni) { s[ni][r] *= 0.125f; mx = fmaxf(mx, s[ni][r]); }
            mx = fmaxf(mx, __shfl_xor(mx, 1));
            mx = fmaxf(mx, __shfl_xor(mx, 2));
            mx = fmaxf(mx, __shfl_xor(mx, 4));
            mx = fmaxf(mx, __shfl_xor(mx, 8));
            float nm = fmaxf(m[r], mx);
            float c = __expf(m[r] - nm);
            m[r] = nm;
            float ps = 0.f;
#pragma unroll
            for (int ni = 0; ni < 4; ++ni) { s[ni][r] = __expf(s[ni][r] - nm); ps += s[ni][r]; }
            ps += __shfl_xor(ps, 1);
            ps += __shfl_xor(ps, 2);
            ps += __shfl_xor(ps, 4);
            ps += __shfl_xor(ps, 8);
            lsum[r] = lsum[r] * c + ps;
            csc[r] = c;
#pragma unroll
            for (int ni = 0; ni < 4; ++ni)
                Ps[w][l4*4 + r][ni*16 + l15] = f2bf(s[ni][r]);
        }
#pragma unroll
        for (int di = 0; di < 4; ++di)
#pragma unroll
            for (int r = 0; r < 4; ++r) o[di][r] *= csc[r];
        bf16x8 ap[2];
        ap[0] = *(const bf16x8*)&Ps[w][l15][l4*8];
        ap[1] = *(const bf16x8*)&Ps[w][l15][32 + l4*8];
#pragma unroll
        for (int kk = 0; kk < 2; ++kk)
#pragma unroll
            for (int di = 0; di < 4; ++di) {
                bf16x8 bv = *(const bf16x8*)&Vt[di*16 + l15][kk*32 + l4*8];
                o[di] = __builtin_amdgcn_mfma_f32_16x16x32_bf16(ap[kk], bv, o[di], 0, 0, 0);
            }
    }
    float inv[4];
#pragma unroll
    for (int r = 0; r < 4; ++r) inv[r] = 1.f / lsum[r];
#pragma unroll
    for (int di = 0; di < 4; ++di)
#pragma unroll
        for (int r = 0; r < 4; ++r)
            out[(size_t)(t0 + w*16 + l4*4 + r) * DIMD + h * DHD + di*16 + l15] = f2bf(o[di][r] * inv[r]);
}

// ---------------- fused residual + LayerNorm ----------------
__global__ __launch_bounds__(256) void k_ln(float* __restrict__ x, const float* __restrict__ f,
                                            const float* __restrict__ g, const float* __restrict__ b)
{
    const int t = blockIdx.x, tid = threadIdx.x;
    __shared__ float y[DIMD];
    __shared__ float red[256];
    float* xr = x + (size_t)t * DIMD;
    const float* fr = f + (size_t)t * DIMD;
    float s = 0.f;
    for (int d = tid; d < DIMD; d += 256) { float v = xr[d] + fr[d]; y[d] = v; s += v; }
    red[tid] = s; __syncthreads();
    for (int off = 128; off > 0; off >>= 1) { if (tid < off) red[tid] += red[tid + off]; __syncthreads(); }
    const float mean = red[0] * (1.f / DIMD);
    __syncthreads();
    s = 0.f;
    for (int d = tid; d < DIMD; d += 256) { float v = y[d] - mean; s += v * v; }
    red[tid] = s; __syncthreads();
    for (int off = 128; off > 0; off >>= 1) { if (tid < off) red[tid] += red[tid + off]; __syncthreads(); }
    const float rstd = 1.f / sqrtf(red[0] * (1.f / DIMD) + 1e-5f);
    for (int d = tid; d < DIMD; d += 256) xr[d] = (y[d] - mean) * rstd * g[d] + b[d];
}

// ---------------- MoE gating ----------------
__global__ __launch_bounds__(256) void k_gate(const float* __restrict__ x,
                                              const float* __restrict__ gAw, const float* __restrict__ gAb,
                                              const float* __restrict__ gBw, const float* __restrict__ gBb,
                                              float* __restrict__ sums, int* __restrict__ cnts,
                                              int* __restrict__ e_id)
{
    const int tid = threadIdx.x, lane = tid & 63, wid = tid >> 6;
    const int gw = blockIdx.x * 4 + wid;
    float wA0[12], wA1[12], wB0[12], wB1[12];
#pragma unroll
    for (int i = 0; i < 12; ++i) {
        int d = lane + i * 64;
        wA0[i] = gAw[d]; wA1[i] = gAw[DIMD + d];
        wB0[i] = gBw[d]; wB1[i] = gBw[DIMD + d];
    }
    const float bA0 = gAb[0], bA1 = gAb[1], bB0 = gBb[0], bB1 = gBb[1];
    float sA0 = 0.f, sA1 = 0.f, sB0 = 0.f, sB1 = 0.f;
    int cA1 = 0, cB1 = 0, cE0 = 0, cE1 = 0, cE2 = 0;
    for (int i = 0; i < 32; ++i) {
        int t = gw * 32 + i;
        const float* xr = x + (size_t)t * DIMD;
        float a0 = 0.f, a1 = 0.f, b0 = 0.f, b1 = 0.f;
#pragma unroll
        for (int j = 0; j < 12; ++j) {
            float v = xr[lane + j * 64];
            a0 = fmaf(v, wA0[j], a0); a1 = fmaf(v, wA1[j], a1);
            b0 = fmaf(v, wB0[j], b0); b1 = fmaf(v, wB1[j], b1);
        }
#pragma unroll
        for (int off = 1; off < 64; off <<= 1) {
            a0 += __shfl_xor(a0, off); a1 += __shfl_xor(a1, off);
            b0 += __shfl_xor(b0, off); b1 += __shfl_xor(b1, off);
        }
        a0 += bA0; a1 += bA1; b0 += bB0; b1 += bB1;
        int iA = (a1 > a0) ? 1 : 0;
        int iB = (b1 > b0) ? 1 : 0;
        float mA = fmaxf(a0, a1); float eA0 = __expf(a0 - mA), eA1 = __expf(a1 - mA);
        float dA = 1.f / (eA0 + eA1);
        float mB = fmaxf(b0, b1); float eB0 = __expf(b0 - mB), eB1 = __expf(b1 - mB);
        float dB = 1.f / (eB0 + eB1);
        sA0 += eA0 * dA; sA1 += eA1 * dA;
        sB0 += eB0 * dB; sB1 += eB1 * dB;
        cA1 += iA; cB1 += iB;
        int e = iA * 2 + iB;
        cE0 += (e == 0); cE1 += (e == 1); cE2 += (e == 2);
        if (lane == 0) e_id[t] = e;
    }
    __shared__ float fpart[4][4];
    __shared__ int   ipart[4][8];
    if (lane == 0) {
        fpart[wid][0] = sA0; fpart[wid][1] = sA1; fpart[wid][2] = sB0; fpart[wid][3] = sB1;
        ipart[wid][0] = 32 - cA1; ipart[wid][1] = cA1;
        ipart[wid][2] = 32 - cB1; ipart[wid][3] = cB1;
        ipart[wid][4] = cE0; ipart[wid][5] = cE1; ipart[wid][6] = cE2;
        ipart[wid][7] = 32 - cE0 - cE1 - cE2;
    }
    __syncthreads();
    if (tid < 4)  atomicAdd(sums + tid, fpart[0][tid] + fpart[1][tid] + fpart[2][tid] + fpart[3][tid]);
    else if (tid >= 64 && tid < 72) {
        int k = tid - 64;
        atomicAdd(cnts + k, ipart[0][k] + ipart[1][k] + ipart[2][k] + ipart[3][k]);
    }
}

__global__ void k_offsets(const int* __restrict__ cntE, int* __restrict__ offs, int* __restrict__ cursor)
{
    if (threadIdx.x == 0) {
        int a = 0;
        for (int e = 0; e < NEXP; ++e) { offs[e] = a; a += cntE[e]; cursor[e] = 0; }
        offs[NEXP] = a;
    }
}

__global__ __launch_bounds__(256) void k_scatter(const int* __restrict__ e_id, const int* __restrict__ offs,
                                                 int* __restrict__ cursor, int* __restrict__ perm)
{
    int t = blockIdx.x * 256 + threadIdx.x;
    int lane = threadIdx.x & 63;
    int e = e_id[t];
#pragma unroll
    for (int eo = 0; eo < NEXP; ++eo) {
        unsigned long long m = __ballot(e == eo);
        if (m == 0ULL) continue;
        int leader = __ffsll((long long)m) - 1;
        int base = 0;
        if (lane == leader) base = atomicAdd(cursor + eo, (int)__popcll(m));
        base = __shfl(base, leader);
        if (e == eo) {
            int lower = (int)__popcll(m & ((1ULL << lane) - 1ULL));
            perm[offs[eo] + base + lower] = t;
        }
    }
}

__global__ void k_aux(const float* __restrict__ sums, const int* __restrict__ cnts, float* __restrict__ aux_acc)
{
    if (threadIdx.x == 0) {
        const float invT2 = 1.f / ((float)TOK * (float)TOK);
        float aA = 2.f * (sums[0] * (float)cnts[0] + sums[1] * (float)cnts[1]) * invT2;
        float aB = 2.f * (sums[2] * (float)cnts[2] + sums[3] * (float)cnts[3]) * invT2;
        *aux_acc += aA + aB;
    }
}

// ---------------- classifier head ----------------
__global__ __launch_bounds__(256) void k_rep(const float* __restrict__ x, float* __restrict__ rep)
{
    int i = blockIdx.x * 256 + threadIdx.x;
    if (i >= NB_ * DIMD) return;
    int b = i / DIMD, d = i % DIMD;
    float s = 0.f;
    for (int q = 0; q < SEQ; ++q) s += x[((size_t)b * SEQ + q) * DIMD + d];
    rep[i] = s * (1.f / SEQ);
}

__global__ __launch_bounds__(256) void k_cls1(const float* __restrict__ rep, const float* __restrict__ cW1,
                                              const float* __restrict__ cB1, float* __restrict__ hcls)
{
    int w = blockIdx.x * 4 + (threadIdx.x >> 6);
    int lane = threadIdx.x & 63;
    if (w >= NB_ * DIMD) return;
    int b = w / DIMD, i = w % DIMD;
    float s = 0.f;
    for (int d = lane; d < DIMD; d += 64) s += rep[b * DIMD + d] * cW1[(size_t)i * DIMD + d];
    for (int off = 32; off > 0; off >>= 1) s += __shfl_down(s, off);
    if (lane == 0) hcls[w] = fmaxf(s + cB1[i], 0.f);
}

__global__ __launch_bounds__(256) void k_cls2(const float* __restrict__ hcls, const float* __restrict__ cW2,
                                              const float* __restrict__ cB2, float* __restrict__ out)
{
    int w = blockIdx.x * 4 + (threadIdx.x >> 6);
    int lane = threadIdx.x & 63;
    if (w >= NB_ * CCLS) return;
    int b = w / CCLS, c = w % CCLS;
    float s = 0.f;
    for (int d = lane; d < DIMD; d += 64) s += hcls[b * DIMD + d] * cW2[(size_t)c * DIMD + d];
    for (int off = 32; off > 0; off >>= 1) s += __shfl_down(s, off);
    if (lane == 0) out[w] = s + cB2[c];
}

__global__ void k_writeaux(const float* __restrict__ aux_acc, float* __restrict__ out)
{
    if (threadIdx.x == 0) out[NB_ * CCLS] = *aux_acc;
}

// ---------------- host launch ----------------
extern "C" void kernel_launch(void* const* d_in, const int* in_sizes, int n_in,
                              void* d_out, int out_size, void* d_ws, size_t ws_size,
                              hipStream_t stream)
{
    const int*   input_ids = (const int*)  d_in[0];
    const float* tok_emb   = (const float*)d_in[1];
    const float* pos_emb   = (const float*)d_in[2];
    const float* wqkv      = (const float*)d_in[3];
    const float* bqkv      = (const float*)d_in[4];
    const float* wo        = (const float*)d_in[5];
    const float* bo        = (const float*)d_in[6];
    const float* ln1g      = (const float*)d_in[7];
    const float* ln1b      = (const float*)d_in[8];
    const float* ln2g      = (const float*)d_in[9];
    const float* ln2b      = (const float*)d_in[10];
    const float* dW1       = (const float*)d_in[11];
    const float* dB1       = (const float*)d_in[12];
    const float* dW2       = (const float*)d_in[13];
    const float* dB2       = (const float*)d_in[14];
    const float* mW1       = (const float*)d_in[15];
    const float* mB1       = (const float*)d_in[16];
    const float* mW2       = (const float*)d_in[17];
    const float* mB2       = (const float*)d_in[18];
    const float* gAw       = (const float*)d_in[19];
    const float* gAb       = (const float*)d_in[20];
    const float* gBw       = (const float*)d_in[21];
    const float* gBb       = (const float*)d_in[22];
    const float* cW1       = (const float*)d_in[23];
    const float* cB1       = (const float*)d_in[24];
    const float* cW2       = (const float*)d_in[25];
    const float* cB2       = (const float*)d_in[26];

    float* out = (float*)d_out;
    float* ws  = (float*)d_ws;

    float*  X    = ws + OFF_X;
    float*  F    = ws + OFF_F;
    ushort* QKV  = (ushort*)(ws + OFF_QKV);
    ushort* Hb   = (ushort*)(ws + OFF_H);
    ushort* G    = (ushort*)(ws + OFF_G);
    float*  REP  = ws + OFF_REP;
    float*  HCLS = ws + OFF_HCLS;
    float*  SUMS = ws + OFF_STAT;
    int*    CNTS = (int*)(ws + OFF_INT);
    int*    OFFS = CNTS + 8;
    int*    CURS = CNTS + 13;
    float*  AUXP = ws + OFF_AUX;
    int*    EID  = (int*)(ws + OFF_EID);
    int*    PERM = (int*)(ws + OFF_PERM);

    hipMemsetAsync(AUXP, 0, sizeof(float), stream);

    k_embed<<<dim3((TOK * DIMD / 4) / 256), 256, 0, stream>>>(input_ids, tok_emb, pos_emb, X);

    int di = 0, mi = 0;
    for (int l = 0; l < 6; ++l) {
        // QKV projection (fp32 X -> bf16 QKV)
        k_gemm_t<0,1><<<dim3(3 * DIMD / 128, TOK / 128), 256, 0, stream>>>(
            X, wqkv + (size_t)l * 3 * DIMD * DIMD, bqkv + (size_t)l * 3 * DIMD, QKV, TOK, 3 * DIMD, DIMD);
        // MFMA flash attention -> G (bf16)
        k_attn<<<dim3(NB_ * NH, SEQ / 64), 256, 0, stream>>>(QKV, G);
        // output projection (bf16 G -> fp32 F)
        k_gemm_t<1,0><<<dim3(DIMD / 128, TOK / 128), 256, 0, stream>>>(
            G, wo + (size_t)l * DIMD * DIMD, bo + (size_t)l * DIMD, F, TOK, DIMD, DIMD);
        k_ln<<<TOK, 256, 0, stream>>>(X, F, ln1g + (size_t)l * DIMD, ln1b + (size_t)l * DIMD);

        if (l == 1 || l == 3 || l == 5) {
            hipMemsetAsync(SUMS, 0, (8 + 24) * sizeof(float), stream);
            k_gate<<<64, 256, 0, stream>>>(X,
                gAw + (size_t)mi * 2 * DIMD, gAb + (size_t)mi * 2,
                gBw + (size_t)mi * 2 * DIMD, gBb + (size_t)mi * 2,
                SUMS, CNTS, EID);
            k_offsets<<<1, 1, 0, stream>>>(CNTS + 4, OFFS, CURS);
            k_scatter<<<TOK / 256, 256, 0, stream>>>(EID, OFFS, CURS, PERM);
            for (int e = 0; e < NEXP; ++e) {
                const float* w1 = mW1 + ((size_t)mi * NEXP + e) * 2 * FFD * DIMD;
                const float* b1 = mB1 + ((size_t)mi * NEXP + e) * 2 * FFD;
                const float* w2 = mW2 + ((size_t)mi * NEXP + e) * (size_t)DIMD * FFD;
                const float* b2 = mB2 + ((size_t)mi * NEXP + e) * DIMD;
                for (int c = 0; c < TOK / CHUNK; ++c) {
                    k_moe_t<1,0,1><<<dim3(2 * FFD / 128, CHUNK / 128), 256, 0, stream>>>(
                        X, w1, b1, Hb, PERM, OFFS, e, c, 2 * FFD, DIMD, 2 * FFD);
                    k_glu<<<dim3((CHUNK * FFD / 8) / 256), 256, 0, stream>>>(Hb, G);
                    k_moe_t<0,1,0><<<dim3(DIMD / 128, CHUNK / 128), 256, 0, stream>>>(
                        G, w2, b2, F, PERM, OFFS, e, c, DIMD, FFD, DIMD);
                }
            }
            k_aux<<<1, 1, 0, stream>>>(SUMS, CNTS, AUXP);
            ++mi;
        } else {
            const float* w1 = dW1 + (size_t)di * 2 * FFD * DIMD;
            const float* b1 = dB1 + (size_t)di * 2 * FFD;
            const float* w2 = dW2 + (size_t)di * (size_t)DIMD * FFD;
            const float* b2 = dB2 + (size_t)di * DIMD;
            for (int c = 0; c < TOK / CHUNK; ++c) {
                k_gemm_t<0,1><<<dim3(2 * FFD / 128, CHUNK / 128), 256, 0, stream>>>(
                    X + (size_t)c * CHUNK * DIMD, w1, b1, Hb, CHUNK, 2 * FFD, DIMD);
                k_glu<<<dim3((CHUNK * FFD / 8) / 256), 256, 0, stream>>>(Hb, G);
                k_gemm_t<1,0><<<dim3(DIMD / 128, CHUNK / 128), 256, 0, stream>>>(
                    G, w2, b2, F + (size_t)c * CHUNK * DIMD, CHUNK, DIMD, FFD);
            }
            ++di;
        }
        k_ln<<<TOK, 256, 0, stream>>>(X, F, ln2g + (size_t)l * DIMD, ln2b + (size_t)l * DIMD);
    }

    k_rep<<<dim3((NB_ * DIMD + 255) / 256), 256, 0, stream>>>(X, REP);
    k_cls1<<<dim3(NB_ * DIMD / 4), 256, 0, stream>>>(REP, cW1, cB1, HCLS);
    k_cls2<<<dim3((NB_ * CCLS + 3) / 4), 256, 0, stream>>>(HCLS, cW2, cB2, out);
    k_writeaux<<<1, 1, 0, stream>>>(AUXP, out);
}

// Round 4
// 4392.019 us; speedup vs baseline: 5.0098x; 1.7076x over previous
//
#include <hip/hip_runtime.h>
#include <cstddef>

#define TOK   8192
#define DIMD  768
#define NH    12
#define DHD   64
#define SEQ   512
#define NB_   16
#define FFD   3072
#define NEXP  4
#define CCLS  10
#define FF2   (2*FFD)

typedef short bf16x8 __attribute__((ext_vector_type(8)));
typedef float f32x4  __attribute__((ext_vector_type(4)));

// ---------------- workspace layout (float-slot units) ----------------
static const size_t OFF_X    = 0;                                   // TOK*D fp32
static const size_t OFF_XB   = OFF_X   + (size_t)TOK*DIMD;          // TOK*D bf16
static const size_t OFF_F    = OFF_XB  + (size_t)TOK*DIMD/2;        // TOK*D fp32
static const size_t OFF_SH   = OFF_F   + (size_t)TOK*DIMD;          // shared: QKV+G | Hh
static const size_t SH_FL    = (size_t)8704*FF2/2;                  // 8704 rows x 6144 bf16
static const size_t OFF_REP  = OFF_SH  + SH_FL;
static const size_t OFF_HCLS = OFF_REP + (size_t)NB_*DIMD;
static const size_t OFF_STAT = OFF_HCLS+ (size_t)NB_*DIMD;          // sums[4]+pad[4]
static const size_t OFF_INT  = OFF_STAT+ 8;                         // 160 int slots
static const size_t OFF_AUX  = OFF_INT + 160;
static const size_t OFF_EID  = OFF_AUX + 1;                         // TOK ints
static const size_t OFF_PERM = OFF_EID + TOK;                       // TOK ints
// INT map: CNTS[0..7], OFFS[8..12], CURS[13..16], NBLK[17], BLKE[18..85], BLKB[86..153]

__device__ __forceinline__ ushort f2bf(float f) {
    union { float f; unsigned u; } v; v.f = f;
    unsigned r = v.u + 0x7FFF + ((v.u >> 16) & 1);   // RNE
    return (ushort)(r >> 16);
}
__device__ __forceinline__ float bf2f(ushort u) {
    union { unsigned u; float f; } v; v.u = ((unsigned)u) << 16;
    return v.f;
}

// ---------------- embedding: X fp32 + Xb bf16 ----------------
__global__ __launch_bounds__(256) void k_embed(const int* __restrict__ ids,
                                               const float* __restrict__ te,
                                               const float* __restrict__ pe,
                                               float* __restrict__ x,
                                               ushort* __restrict__ xb)
{
    int i = blockIdx.x * 256 + threadIdx.x;
    const int nd4 = DIMD / 4;
    if (i >= TOK * nd4) return;
    int t = i / nd4, d4 = i % nd4;
    int s = t % SEQ;
    int id = ids[t];
    float4 a = ((const float4*)(te + (size_t)id * DIMD))[d4];
    float4 b = ((const float4*)(pe + (size_t)s  * DIMD))[d4];
    float4 o; o.x = a.x + b.x; o.y = a.y + b.y; o.z = a.z + b.z; o.w = a.w + b.w;
    ((float4*)(x + (size_t)t * DIMD))[d4] = o;
    ushort4 ob = make_ushort4(f2bf(o.x), f2bf(o.y), f2bf(o.z), f2bf(o.w));
    *(ushort4*)(xb + (size_t)t * DIMD + d4 * 4) = ob;
}

// ---------------- bf16-A MFMA GEMM: C[m,n] = A[m,:]*W[n,:] + bias[n] ----------------
template<int CBF>
__global__ __launch_bounds__(256) void k_gemm(const ushort* __restrict__ A,
                                              const float* __restrict__ W,
                                              const float* __restrict__ bias,
                                              void* __restrict__ C_,
                                              int M, int N, int K)
{
    __shared__ ushort As[128][40];
    __shared__ ushort Bs[128][40];
    const int tid = threadIdx.x;
    const int lane = tid & 63, wid = tid >> 6;
    const int wm = wid >> 1, wn = wid & 1;
    const int m0 = blockIdx.y * 128, n0 = blockIdx.x * 128;
    const int l15 = lane & 15, l4 = lane >> 4;
    const int srow = tid >> 2, sc8 = (tid & 3) * 8;
    const int strow = tid >> 3, stc = (tid & 7) * 4;
    f32x4 acc[4][4] = {};
    for (int k0 = 0; k0 < K; k0 += 32) {
        uint4 av8[2]; float4 bv[4];
#pragma unroll
        for (int it = 0; it < 2; ++it)
            av8[it] = *(const uint4*)(A + (size_t)(m0 + it * 64 + srow) * K + k0 + sc8);
#pragma unroll
        for (int it = 0; it < 4; ++it)
            bv[it] = *(const float4*)(W + (size_t)(n0 + it * 32 + strow) * K + k0 + stc);
        __syncthreads();
#pragma unroll
        for (int it = 0; it < 2; ++it)
            *(uint4*)&As[it * 64 + srow][sc8] = av8[it];
#pragma unroll
        for (int it = 0; it < 4; ++it) {
            float4 w4 = bv[it];
            *(ushort4*)&Bs[it * 32 + strow][stc] = make_ushort4(f2bf(w4.x), f2bf(w4.y), f2bf(w4.z), f2bf(w4.w));
        }
        __syncthreads();
        bf16x8 af[4], bfr[4];
#pragma unroll
        for (int i = 0; i < 4; ++i) {
            af[i]  = *(const bf16x8*)&As[wm*64 + i*16 + l15][l4*8];
            bfr[i] = *(const bf16x8*)&Bs[wn*64 + i*16 + l15][l4*8];
        }
#pragma unroll
        for (int mi = 0; mi < 4; ++mi)
#pragma unroll
            for (int ni = 0; ni < 4; ++ni)
                acc[mi][ni] = __builtin_amdgcn_mfma_f32_16x16x32_bf16(af[mi], bfr[ni], acc[mi][ni], 0, 0, 0);
    }
#pragma unroll
    for (int ni = 0; ni < 4; ++ni) {
        int col = n0 + wn*64 + ni*16 + l15;
        float bb = bias[col];
#pragma unroll
        for (int mi = 0; mi < 4; ++mi) {
            int row = m0 + wm*64 + mi*16 + l4*4;
#pragma unroll
            for (int r = 0; r < 4; ++r) {
                float o = acc[mi][ni][r] + bb;
                if constexpr (CBF) ((ushort*)C_)[(size_t)(row + r) * N + col] = f2bf(o);
                else               ((float*)C_)[(size_t)(row + r) * N + col] = o;
            }
        }
    }
}

// ---------------- W1 GEMM: Xb (bf16, gathered if MOE) x W1 -> Hh bf16 ----------------
// Single dispatch covers all experts via block->expert map (128-row padded).
template<int MOE>
__global__ __launch_bounds__(256) void k_w1(const ushort* __restrict__ Xb,
                                            const float* __restrict__ W1,
                                            const float* __restrict__ B1,
                                            ushort* __restrict__ Hh,
                                            const int* __restrict__ perm,
                                            const int* __restrict__ offs,
                                            const int* __restrict__ blke,
                                            const int* __restrict__ blkb,
                                            const int* __restrict__ nblk)
{
    __shared__ ushort As[128][40];
    __shared__ ushort Bs[128][40];
    __shared__ int    toks[128];
    const int rb = blockIdx.y;
    const float* W = W1; const float* bias = B1;
    if constexpr (MOE) {
        if (rb >= *nblk) return;
        int e = blke[rb];
        int lb = blkb[rb];
        int base = offs[e], cnt = offs[e + 1] - base;
        W    = W1 + (size_t)e * FF2 * DIMD;
        bias = B1 + (size_t)e * FF2;
        if (threadIdx.x < 128) {
            int rg = lb + threadIdx.x;
            toks[threadIdx.x] = perm[base + (rg < cnt ? rg : cnt - 1)];
        }
        __syncthreads();
    }
    const int tid = threadIdx.x, lane = tid & 63, wid = tid >> 6;
    const int wm = wid >> 1, wn = wid & 1;
    const int n0 = blockIdx.x * 128;
    const int row0 = rb * 128;
    const int l15 = lane & 15, l4 = lane >> 4;
    const int srow = tid >> 2, sc8 = (tid & 3) * 8;
    const int strow = tid >> 3, stc = (tid & 7) * 4;
    f32x4 acc[4][4] = {};
    for (int k0 = 0; k0 < DIMD; k0 += 32) {
        uint4 av8[2]; float4 bv[4];
#pragma unroll
        for (int it = 0; it < 2; ++it) {
            int r = it * 64 + srow;
            int arow = MOE ? toks[r] : (row0 + r);
            av8[it] = *(const uint4*)(Xb + (size_t)arow * DIMD + k0 + sc8);
        }
#pragma unroll
        for (int it = 0; it < 4; ++it)
            bv[it] = *(const float4*)(W + (size_t)(n0 + it * 32 + strow) * DIMD + k0 + stc);
        __syncthreads();
#pragma unroll
        for (int it = 0; it < 2; ++it)
            *(uint4*)&As[it * 64 + srow][sc8] = av8[it];
#pragma unroll
        for (int it = 0; it < 4; ++it) {
            float4 w4 = bv[it];
            *(ushort4*)&Bs[it * 32 + strow][stc] = make_ushort4(f2bf(w4.x), f2bf(w4.y), f2bf(w4.z), f2bf(w4.w));
        }
        __syncthreads();
        bf16x8 af[4], bfr[4];
#pragma unroll
        for (int i = 0; i < 4; ++i) {
            af[i]  = *(const bf16x8*)&As[wm*64 + i*16 + l15][l4*8];
            bfr[i] = *(const bf16x8*)&Bs[wn*64 + i*16 + l15][l4*8];
        }
#pragma unroll
        for (int mi = 0; mi < 4; ++mi)
#pragma unroll
            for (int ni = 0; ni < 4; ++ni)
                acc[mi][ni] = __builtin_amdgcn_mfma_f32_16x16x32_bf16(af[mi], bfr[ni], acc[mi][ni], 0, 0, 0);
    }
#pragma unroll
    for (int ni = 0; ni < 4; ++ni) {
        int col = n0 + wn*64 + ni*16 + l15;
        float bb = bias[col];
#pragma unroll
        for (int mi = 0; mi < 4; ++mi) {
            int row = row0 + wm*64 + mi*16 + l4*4;
#pragma unroll
            for (int r = 0; r < 4; ++r)
                Hh[(size_t)(row + r) * FF2 + col] = f2bf(acc[mi][ni][r] + bb);
        }
    }
}

// ---------------- W2 GEMM with fused GLU staging: F = (a*silu(b)) x W2 + bias ----------------
template<int MOE>
__global__ __launch_bounds__(256) void k_w2(const ushort* __restrict__ Hh,
                                            const float* __restrict__ W2,
                                            const float* __restrict__ B2,
                                            float* __restrict__ F,
                                            const int* __restrict__ perm,
                                            const int* __restrict__ offs,
                                            const int* __restrict__ blke,
                                            const int* __restrict__ blkb,
                                            const int* __restrict__ nblk)
{
    __shared__ ushort As[128][40];
    __shared__ ushort Bs[128][40];
    __shared__ int    toks[128];
    const int rb = blockIdx.y;
    const float* W = W2; const float* bias = B2;
    int lb = 0, cnt = 1 << 30;
    if constexpr (MOE) {
        if (rb >= *nblk) return;
        int e = blke[rb];
        lb = blkb[rb];
        int base = offs[e]; cnt = offs[e + 1] - base;
        W    = W2 + (size_t)e * DIMD * FFD;
        bias = B2 + (size_t)e * DIMD;
        if (threadIdx.x < 128) {
            int rg = lb + threadIdx.x;
            toks[threadIdx.x] = perm[base + (rg < cnt ? rg : cnt - 1)];
        }
        __syncthreads();
    }
    const int tid = threadIdx.x, lane = tid & 63, wid = tid >> 6;
    const int wm = wid >> 1, wn = wid & 1;
    const int n0 = blockIdx.x * 128;
    const int row0 = rb * 128;
    const int l15 = lane & 15, l4 = lane >> 4;
    const int srow = tid >> 2, sc8 = (tid & 3) * 8;
    const int strow = tid >> 3, stc = (tid & 7) * 4;
    f32x4 acc[4][4] = {};
    for (int k0 = 0; k0 < FFD; k0 += 32) {
        uint4 ga[2]; float4 bv[4];
#pragma unroll
        for (int it = 0; it < 2; ++it) {
            int g = row0 + it * 64 + srow;
            uint4 a8 = *(const uint4*)(Hh + (size_t)g * FF2 + k0 + sc8);
            uint4 b8 = *(const uint4*)(Hh + (size_t)g * FF2 + FFD + k0 + sc8);
            const ushort* ap = (const ushort*)&a8;
            const ushort* bp = (const ushort*)&b8;
            ushort res[8];
#pragma unroll
            for (int j = 0; j < 8; ++j) {
                float a = bf2f(ap[j]), b = bf2f(bp[j]);
                res[j] = f2bf(a * (b / (1.f + __expf(-b))));
            }
            ga[it] = *(const uint4*)res;
        }
#pragma unroll
        for (int it = 0; it < 4; ++it)
            bv[it] = *(const float4*)(W + (size_t)(n0 + it * 32 + strow) * FFD + k0 + stc);
        __syncthreads();
#pragma unroll
        for (int it = 0; it < 2; ++it)
            *(uint4*)&As[it * 64 + srow][sc8] = ga[it];
#pragma unroll
        for (int it = 0; it < 4; ++it) {
            float4 w4 = bv[it];
            *(ushort4*)&Bs[it * 32 + strow][stc] = make_ushort4(f2bf(w4.x), f2bf(w4.y), f2bf(w4.z), f2bf(w4.w));
        }
        __syncthreads();
        bf16x8 af[4], bfr[4];
#pragma unroll
        for (int i = 0; i < 4; ++i) {
            af[i]  = *(const bf16x8*)&As[wm*64 + i*16 + l15][l4*8];
            bfr[i] = *(const bf16x8*)&Bs[wn*64 + i*16 + l15][l4*8];
        }
#pragma unroll
        for (int mi = 0; mi < 4; ++mi)
#pragma unroll
            for (int ni = 0; ni < 4; ++ni)
                acc[mi][ni] = __builtin_amdgcn_mfma_f32_16x16x32_bf16(af[mi], bfr[ni], acc[mi][ni], 0, 0, 0);
    }
#pragma unroll
    for (int ni = 0; ni < 4; ++ni) {
        int col = n0 + wn*64 + ni*16 + l15;
        float bb = bias[col];
#pragma unroll
        for (int mi = 0; mi < 4; ++mi) {
            int ri = wm*64 + mi*16 + l4*4;
#pragma unroll
            for (int r = 0; r < 4; ++r) {
                float o = acc[mi][ni][r] + bb;
                if constexpr (MOE) {
                    if (lb + ri + r < cnt)
                        F[(size_t)toks[ri + r] * DIMD + col] = o;
                } else {
                    F[(size_t)(row0 + ri + r) * DIMD + col] = o;
                }
            }
        }
    }
}

// ---------------- MFMA flash attention (unchanged from R3) ----------------
__global__ __launch_bounds__(256) void k_attn(const ushort* __restrict__ qkv, ushort* __restrict__ out)
{
    __shared__ ushort Qs[64][72];
    __shared__ ushort Ks[64][72];
    __shared__ ushort Vt[64][72];
    __shared__ ushort Ps[4][16][72];
    const int bh = blockIdx.x;
    const int b = bh / NH, h = bh % NH;
    const int qt = blockIdx.y;
    const int tid = threadIdx.x, lane = tid & 63, w = tid >> 6;
    const int l15 = lane & 15, l4 = lane >> 4;
    const int t0 = b * SEQ + qt * 64;
    {
        int r = tid >> 3, c8 = (tid & 7) * 8;
#pragma unroll
        for (int p = 0; p < 2; ++p) {
            int rr = r + p * 32;
            *(uint4*)&Qs[rr][c8] = *(const uint4*)(qkv + (size_t)(t0 + rr) * 3 * DIMD + h * DHD + c8);
        }
    }
    __syncthreads();
    bf16x8 aq[2];
    aq[0] = *(const bf16x8*)&Qs[w*16 + l15][l4*8];
    aq[1] = *(const bf16x8*)&Qs[w*16 + l15][32 + l4*8];
    f32x4 o[4] = {};
    float m[4], lsum[4];
#pragma unroll
    for (int r = 0; r < 4; ++r) { m[r] = -3.0e38f; lsum[r] = 0.f; }
    for (int kt = 0; kt < SEQ; kt += 64) {
        __syncthreads();
        {
            int r = tid >> 3, c8 = (tid & 7) * 8;
#pragma unroll
            for (int p = 0; p < 2; ++p) {
                int rr = r + p * 32;
                const ushort* kp = qkv + (size_t)(b * SEQ + kt + rr) * 3 * DIMD + DIMD + h * DHD;
                *(uint4*)&Ks[rr][c8] = *(const uint4*)(kp + c8);
                uint4 vv = *(const uint4*)(kp + DIMD + c8);
                const ushort* vs = (const ushort*)&vv;
#pragma unroll
                for (int j = 0; j < 8; ++j) Vt[c8 + j][rr] = vs[j];
            }
        }
        __syncthreads();
        f32x4 s[4] = {};
#pragma unroll
        for (int kk = 0; kk < 2; ++kk)
#pragma unroll
            for (int ni = 0; ni < 4; ++ni) {
                bf16x8 bk = *(const bf16x8*)&Ks[ni*16 + l15][kk*32 + l4*8];
                s[ni] = __builtin_amdgcn_mfma_f32_16x16x32_bf16(aq[kk], bk, s[ni], 0, 0, 0);
            }
        float csc[4];
#pragma unroll
        for (int r = 0; r < 4; ++r) {
            float mx = -3.0e38f;
#pragma unroll
            for (int ni = 0; ni < 4; ++ni) { s[ni][r] *= 0.125f; mx = fmaxf(mx, s[ni][r]); }
            mx = fmaxf(mx, __shfl_xor(mx, 1));
            mx = fmaxf(mx, __shfl_xor(mx, 2));
            mx = fmaxf(mx, __shfl_xor(mx, 4));
            mx = fmaxf(mx, __shfl_xor(mx, 8));
            float nm = fmaxf(m[r], mx);
            float c = __expf(m[r] - nm);
            m[r] = nm;
            float ps = 0.f;
#pragma unroll
            for (int ni = 0; ni < 4; ++ni) { s[ni][r] = __expf(s[ni][r] - nm); ps += s[ni][r]; }
            ps += __shfl_xor(ps, 1);
            ps += __shfl_xor(ps, 2);
            ps += __shfl_xor(ps, 4);
            ps += __shfl_xor(ps, 8);
            lsum[r] = lsum[r] * c + ps;
            csc[r] = c;
#pragma unroll
            for (int ni = 0; ni < 4; ++ni)
                Ps[w][l4*4 + r][ni*16 + l15] = f2bf(s[ni][r]);
        }
#pragma unroll
        for (int di = 0; di < 4; ++di)
#pragma unroll
            for (int r = 0; r < 4; ++r) o[di][r] *= csc[r];
        bf16x8 ap[2];
        ap[0] = *(const bf16x8*)&Ps[w][l15][l4*8];
        ap[1] = *(const bf16x8*)&Ps[w][l15][32 + l4*8];
#pragma unroll
        for (int kk = 0; kk < 2; ++kk)
#pragma unroll
            for (int di = 0; di < 4; ++di) {
                bf16x8 bv = *(const bf16x8*)&Vt[di*16 + l15][kk*32 + l4*8];
                o[di] = __builtin_amdgcn_mfma_f32_16x16x32_bf16(ap[kk], bv, o[di], 0, 0, 0);
            }
    }
    float inv[4];
#pragma unroll
    for (int r = 0; r < 4; ++r) inv[r] = 1.f / lsum[r];
#pragma unroll
    for (int di = 0; di < 4; ++di)
#pragma unroll
        for (int r = 0; r < 4; ++r)
            out[(size_t)(t0 + w*16 + l4*4 + r) * DIMD + h * DHD + di*16 + l15] = f2bf(o[di][r] * inv[r]);
}

// ---------------- fused residual + LayerNorm -> X fp32 + Xb bf16 ----------------
__global__ __launch_bounds__(256) void k_ln(float* __restrict__ x, const float* __restrict__ f,
                                            const float* __restrict__ g, const float* __restrict__ b,
                                            ushort* __restrict__ xb)
{
    const int t = blockIdx.x, tid = threadIdx.x;
    __shared__ float y[DIMD];
    __shared__ float red[256];
    float* xr = x + (size_t)t * DIMD;
    const float* fr = f + (size_t)t * DIMD;
    float s = 0.f;
    for (int d = tid; d < DIMD; d += 256) { float v = xr[d] + fr[d]; y[d] = v; s += v; }
    red[tid] = s; __syncthreads();
    for (int off = 128; off > 0; off >>= 1) { if (tid < off) red[tid] += red[tid + off]; __syncthreads(); }
    const float mean = red[0] * (1.f / DIMD);
    __syncthreads();
    s = 0.f;
    for (int d = tid; d < DIMD; d += 256) { float v = y[d] - mean; s += v * v; }
    red[tid] = s; __syncthreads();
    for (int off = 128; off > 0; off >>= 1) { if (tid < off) red[tid] += red[tid + off]; __syncthreads(); }
    const float rstd = 1.f / sqrtf(red[0] * (1.f / DIMD) + 1e-5f);
    for (int d = tid; d < DIMD; d += 256) {
        float v = (y[d] - mean) * rstd * g[d] + b[d];
        xr[d] = v;
        xb[(size_t)t * DIMD + d] = f2bf(v);
    }
}

// ---------------- MoE gating ----------------
__global__ __launch_bounds__(256) void k_gate(const float* __restrict__ x,
                                              const float* __restrict__ gAw, const float* __restrict__ gAb,
                                              const float* __restrict__ gBw, const float* __restrict__ gBb,
                                              float* __restrict__ sums, int* __restrict__ cnts,
                                              int* __restrict__ e_id)
{
    const int tid = threadIdx.x, lane = tid & 63, wid = tid >> 6;
    const int gw = blockIdx.x * 4 + wid;
    float wA0[12], wA1[12], wB0[12], wB1[12];
#pragma unroll
    for (int i = 0; i < 12; ++i) {
        int d = lane + i * 64;
        wA0[i] = gAw[d]; wA1[i] = gAw[DIMD + d];
        wB0[i] = gBw[d]; wB1[i] = gBw[DIMD + d];
    }
    const float bA0 = gAb[0], bA1 = gAb[1], bB0 = gBb[0], bB1 = gBb[1];
    float sA0 = 0.f, sA1 = 0.f, sB0 = 0.f, sB1 = 0.f;
    int cA1 = 0, cB1 = 0, cE0 = 0, cE1 = 0, cE2 = 0;
    for (int i = 0; i < 32; ++i) {
        int t = gw * 32 + i;
        const float* xr = x + (size_t)t * DIMD;
        float a0 = 0.f, a1 = 0.f, b0 = 0.f, b1 = 0.f;
#pragma unroll
        for (int j = 0; j < 12; ++j) {
            float v = xr[lane + j * 64];
            a0 = fmaf(v, wA0[j], a0); a1 = fmaf(v, wA1[j], a1);
            b0 = fmaf(v, wB0[j], b0); b1 = fmaf(v, wB1[j], b1);
        }
#pragma unroll
        for (int off = 1; off < 64; off <<= 1) {
            a0 += __shfl_xor(a0, off); a1 += __shfl_xor(a1, off);
            b0 += __shfl_xor(b0, off); b1 += __shfl_xor(b1, off);
        }
        a0 += bA0; a1 += bA1; b0 += bB0; b1 += bB1;
        int iA = (a1 > a0) ? 1 : 0;
        int iB = (b1 > b0) ? 1 : 0;
        float mA = fmaxf(a0, a1); float eA0 = __expf(a0 - mA), eA1 = __expf(a1 - mA);
        float dA = 1.f / (eA0 + eA1);
        float mB = fmaxf(b0, b1); float eB0 = __expf(b0 - mB), eB1 = __expf(b1 - mB);
        float dB = 1.f / (eB0 + eB1);
        sA0 += eA0 * dA; sA1 += eA1 * dA;
        sB0 += eB0 * dB; sB1 += eB1 * dB;
        cA1 += iA; cB1 += iB;
        int e = iA * 2 + iB;
        cE0 += (e == 0); cE1 += (e == 1); cE2 += (e == 2);
        if (lane == 0) e_id[t] = e;
    }
    __shared__ float fpart[4][4];
    __shared__ int   ipart[4][8];
    if (lane == 0) {
        fpart[wid][0] = sA0; fpart[wid][1] = sA1; fpart[wid][2] = sB0; fpart[wid][3] = sB1;
        ipart[wid][0] = 32 - cA1; ipart[wid][1] = cA1;
        ipart[wid][2] = 32 - cB1; ipart[wid][3] = cB1;
        ipart[wid][4] = cE0; ipart[wid][5] = cE1; ipart[wid][6] = cE2;
        ipart[wid][7] = 32 - cE0 - cE1 - cE2;
    }
    __syncthreads();
    if (tid < 4)  atomicAdd(sums + tid, fpart[0][tid] + fpart[1][tid] + fpart[2][tid] + fpart[3][tid]);
    else if (tid >= 64 && tid < 72) {
        int k = tid - 64;
        atomicAdd(cnts + k, ipart[0][k] + ipart[1][k] + ipart[2][k] + ipart[3][k]);
    }
}

// offsets + cursors + block->expert map (padded 128-row blocks)
__global__ void k_offsets(const int* __restrict__ cntE, int* __restrict__ offs, int* __restrict__ cursor,
                          int* __restrict__ nblk, int* __restrict__ blke, int* __restrict__ blkb)
{
    if (threadIdx.x == 0) {
        int a = 0, nb = 0;
        for (int e = 0; e < NEXP; ++e) {
            offs[e] = a; a += cntE[e]; cursor[e] = 0;
            int blocks = (cntE[e] + 127) >> 7;
            for (int b = 0; b < blocks; ++b) { blke[nb] = e; blkb[nb] = b * 128; ++nb; }
        }
        offs[NEXP] = a;
        *nblk = nb;
    }
}

__global__ __launch_bounds__(256) void k_scatter(const int* __restrict__ e_id, const int* __restrict__ offs,
                                                 int* __restrict__ cursor, int* __restrict__ perm)
{
    int t = blockIdx.x * 256 + threadIdx.x;
    int lane = threadIdx.x & 63;
    int e = e_id[t];
#pragma unroll
    for (int eo = 0; eo < NEXP; ++eo) {
        unsigned long long m = __ballot(e == eo);
        if (m == 0ULL) continue;
        int leader = __ffsll((long long)m) - 1;
        int base = 0;
        if (lane == leader) base = atomicAdd(cursor + eo, (int)__popcll(m));
        base = __shfl(base, leader);
        if (e == eo) {
            int lower = (int)__popcll(m & ((1ULL << lane) - 1ULL));
            perm[offs[eo] + base + lower] = t;
        }
    }
}

__global__ void k_aux(const float* __restrict__ sums, const int* __restrict__ cnts, float* __restrict__ aux_acc)
{
    if (threadIdx.x == 0) {
        const float invT2 = 1.f / ((float)TOK * (float)TOK);
        float aA = 2.f * (sums[0] * (float)cnts[0] + sums[1] * (float)cnts[1]) * invT2;
        float aB = 2.f * (sums[2] * (float)cnts[2] + sums[3] * (float)cnts[3]) * invT2;
        *aux_acc += aA + aB;
    }
}

// ---------------- classifier head ----------------
__global__ __launch_bounds__(256) void k_rep(const float* __restrict__ x, float* __restrict__ rep)
{
    int i = blockIdx.x * 256 + threadIdx.x;
    if (i >= NB_ * DIMD) return;
    int b = i / DIMD, d = i % DIMD;
    float s = 0.f;
    for (int q = 0; q < SEQ; ++q) s += x[((size_t)b * SEQ + q) * DIMD + d];
    rep[i] = s * (1.f / SEQ);
}

__global__ __launch_bounds__(256) void k_cls1(const float* __restrict__ rep, const float* __restrict__ cW1,
                                              const float* __restrict__ cB1, float* __restrict__ hcls)
{
    int w = blockIdx.x * 4 + (threadIdx.x >> 6);
    int lane = threadIdx.x & 63;
    if (w >= NB_ * DIMD) return;
    int b = w / DIMD, i = w % DIMD;
    float s = 0.f;
    for (int d = lane; d < DIMD; d += 64) s += rep[b * DIMD + d] * cW1[(size_t)i * DIMD + d];
    for (int off = 32; off > 0; off >>= 1) s += __shfl_down(s, off);
    if (lane == 0) hcls[w] = fmaxf(s + cB1[i], 0.f);
}

__global__ __launch_bounds__(256) void k_cls2(const float* __restrict__ hcls, const float* __restrict__ cW2,
                                              const float* __restrict__ cB2, float* __restrict__ out)
{
    int w = blockIdx.x * 4 + (threadIdx.x >> 6);
    int lane = threadIdx.x & 63;
    if (w >= NB_ * CCLS) return;
    int b = w / CCLS, c = w % CCLS;
    float s = 0.f;
    for (int d = lane; d < DIMD; d += 64) s += hcls[b * DIMD + d] * cW2[(size_t)c * DIMD + d];
    for (int off = 32; off > 0; off >>= 1) s += __shfl_down(s, off);
    if (lane == 0) out[w] = s + cB2[c];
}

__global__ void k_writeaux(const float* __restrict__ aux_acc, float* __restrict__ out)
{
    if (threadIdx.x == 0) out[NB_ * CCLS] = *aux_acc;
}

// ---------------- host launch ----------------
extern "C" void kernel_launch(void* const* d_in, const int* in_sizes, int n_in,
                              void* d_out, int out_size, void* d_ws, size_t ws_size,
                              hipStream_t stream)
{
    const int*   input_ids = (const int*)  d_in[0];
    const float* tok_emb   = (const float*)d_in[1];
    const float* pos_emb   = (const float*)d_in[2];
    const float* wqkv      = (const float*)d_in[3];
    const float* bqkv      = (const float*)d_in[4];
    const float* wo        = (const float*)d_in[5];
    const float* bo        = (const float*)d_in[6];
    const float* ln1g      = (const float*)d_in[7];
    const float* ln1b      = (const float*)d_in[8];
    const float* ln2g      = (const float*)d_in[9];
    const float* ln2b      = (const float*)d_in[10];
    const float* dW1       = (const float*)d_in[11];
    const float* dB1       = (const float*)d_in[12];
    const float* dW2       = (const float*)d_in[13];
    const float* dB2       = (const float*)d_in[14];
    const float* mW1       = (const float*)d_in[15];
    const float* mB1       = (const float*)d_in[16];
    const float* mW2       = (const float*)d_in[17];
    const float* mB2       = (const float*)d_in[18];
    const float* gAw       = (const float*)d_in[19];
    const float* gAb       = (const float*)d_in[20];
    const float* gBw       = (const float*)d_in[21];
    const float* gBb       = (const float*)d_in[22];
    const float* cW1       = (const float*)d_in[23];
    const float* cB1       = (const float*)d_in[24];
    const float* cW2       = (const float*)d_in[25];
    const float* cB2       = (const float*)d_in[26];

    float* out = (float*)d_out;
    float* ws  = (float*)d_ws;

    float*  X    = ws + OFF_X;
    ushort* XB   = (ushort*)(ws + OFF_XB);
    float*  F    = ws + OFF_F;
    ushort* QKV  = (ushort*)(ws + OFF_SH);
    ushort* G    = (ushort*)(ws + OFF_SH + (size_t)TOK * 3 * DIMD / 2);
    ushort* Hh   = (ushort*)(ws + OFF_SH);
    float*  REP  = ws + OFF_REP;
    float*  HCLS = ws + OFF_HCLS;
    float*  SUMS = ws + OFF_STAT;
    int*    INTB = (int*)(ws + OFF_INT);
    int*    CNTS = INTB;            // 8
    int*    OFFS = INTB + 8;        // 5
    int*    CURS = INTB + 13;       // 4
    int*    NBLK = INTB + 17;       // 1
    int*    BLKE = INTB + 18;       // 68
    int*    BLKB = INTB + 86;       // 68
    float*  AUXP = ws + OFF_AUX;
    int*    EID  = (int*)(ws + OFF_EID);
    int*    PERM = (int*)(ws + OFF_PERM);

    hipMemsetAsync(AUXP, 0, sizeof(float), stream);

    k_embed<<<dim3((TOK * DIMD / 4) / 256), 256, 0, stream>>>(input_ids, tok_emb, pos_emb, X, XB);

    int di = 0, mi = 0;
    for (int l = 0; l < 6; ++l) {
        // QKV projection (bf16 Xb -> bf16 QKV)
        k_gemm<1><<<dim3(3 * DIMD / 128, TOK / 128), 256, 0, stream>>>(
            XB, wqkv + (size_t)l * 3 * DIMD * DIMD, bqkv + (size_t)l * 3 * DIMD, QKV, TOK, 3 * DIMD, DIMD);
        // MFMA flash attention -> G (bf16)
        k_attn<<<dim3(NB_ * NH, SEQ / 64), 256, 0, stream>>>(QKV, G);
        // output projection (bf16 G -> fp32 F)
        k_gemm<0><<<dim3(DIMD / 128, TOK / 128), 256, 0, stream>>>(
            G, wo + (size_t)l * DIMD * DIMD, bo + (size_t)l * DIMD, F, TOK, DIMD, DIMD);
        k_ln<<<TOK, 256, 0, stream>>>(X, F, ln1g + (size_t)l * DIMD, ln1b + (size_t)l * DIMD, XB);

        if (l == 1 || l == 3 || l == 5) {
            hipMemsetAsync(SUMS, 0, 64, stream);   // sums[8] + cnts[8]
            k_gate<<<64, 256, 0, stream>>>(X,
                gAw + (size_t)mi * 2 * DIMD, gAb + (size_t)mi * 2,
                gBw + (size_t)mi * 2 * DIMD, gBb + (size_t)mi * 2,
                SUMS, CNTS, EID);
            k_offsets<<<1, 1, 0, stream>>>(CNTS + 4, OFFS, CURS, NBLK, BLKE, BLKB);
            k_scatter<<<TOK / 256, 256, 0, stream>>>(EID, OFFS, CURS, PERM);
            k_w1<1><<<dim3(FF2 / 128, 67), 256, 0, stream>>>(
                XB, mW1 + (size_t)mi * NEXP * FF2 * DIMD, mB1 + (size_t)mi * NEXP * FF2,
                Hh, PERM, OFFS, BLKE, BLKB, NBLK);
            k_w2<1><<<dim3(DIMD / 128, 67), 256, 0, stream>>>(
                Hh, mW2 + (size_t)mi * NEXP * DIMD * FFD, mB2 + (size_t)mi * NEXP * DIMD,
                F, PERM, OFFS, BLKE, BLKB, NBLK);
            k_aux<<<1, 1, 0, stream>>>(SUMS, CNTS, AUXP);
            ++mi;
        } else {
            k_w1<0><<<dim3(FF2 / 128, TOK / 128), 256, 0, stream>>>(
                XB, dW1 + (size_t)di * FF2 * DIMD, dB1 + (size_t)di * FF2,
                Hh, nullptr, nullptr, nullptr, nullptr, nullptr);
            k_w2<0><<<dim3(DIMD / 128, TOK / 128), 256, 0, stream>>>(
                Hh, dW2 + (size_t)di * (size_t)DIMD * FFD, dB2 + (size_t)di * DIMD,
                F, nullptr, nullptr, nullptr, nullptr, nullptr);
            ++di;
        }
        k_ln<<<TOK, 256, 0, stream>>>(X, F, ln2g + (size_t)l * DIMD, ln2b + (size_t)l * DIMD, XB);
    }

    k_rep<<<dim3((NB_ * DIMD + 255) / 256), 256, 0, stream>>>(X, REP);
    k_cls1<<<dim3(NB_ * DIMD / 4), 256, 0, stream>>>(REP, cW1, cB1, HCLS);
    k_cls2<<<dim3((NB_ * CCLS + 3) / 4), 256, 0, stream>>>(HCLS, cW2, cB2, out);
    k_writeaux<<<1, 1, 0, stream>>>(AUXP, out);
}

// Round 5
// 3192.641 us; speedup vs baseline: 6.8918x; 1.3757x over previous
//
#include <hip/hip_runtime.h>
#include <cstddef>

#define TOK   8192
#define DIMD  768
#define NH    12
#define DHD   64
#define SEQ   512
#define NB_   16
#define FFD   3072
#define NEXP  4
#define CCLS  10
#define FF2   (2*FFD)

typedef short bf16x8 __attribute__((ext_vector_type(8)));
typedef float f32x4  __attribute__((ext_vector_type(4)));

// ---------------- workspace layout (float-slot units) ----------------
static const size_t OFF_X    = 0;                                   // TOK*D fp32
static const size_t OFF_XB   = OFF_X   + (size_t)TOK*DIMD;          // TOK*D bf16
static const size_t OFF_F    = OFF_XB  + (size_t)TOK*DIMD/2;        // TOK*D fp32
static const size_t OFF_SH   = OFF_F   + (size_t)TOK*DIMD;          // shared: QKV+G | Hh
static const size_t SH_FL    = (size_t)8704*FF2/2;                  // Hh: 8704 x 6144 bf16
static const size_t OFF_WQ   = OFF_SH  + SH_FL;                     // qkv weights bf16
static const size_t OFF_WOB  = OFF_WQ  + (size_t)3*DIMD*DIMD/2;
static const size_t OFF_W1B  = OFF_WOB + (size_t)DIMD*DIMD/2;       // up to 4 experts
static const size_t OFF_W2B  = OFF_W1B + (size_t)NEXP*FF2*DIMD/2;
static const size_t OFF_REP  = OFF_W2B + (size_t)NEXP*DIMD*FFD/2;
static const size_t OFF_HCLS = OFF_REP + (size_t)NB_*DIMD;
static const size_t OFF_STAT = OFF_HCLS+ (size_t)NB_*DIMD;          // sums[4]+pad
static const size_t OFF_INT  = OFF_STAT+ 8;                         // 160 int slots
static const size_t OFF_AUX  = OFF_INT + 160;
static const size_t OFF_EID  = OFF_AUX + 1;                         // TOK ints
static const size_t OFF_PERM = OFF_EID + TOK;                       // TOK ints

__device__ __forceinline__ ushort f2bf(float f) {
    union { float f; unsigned u; } v; v.f = f;
    unsigned r = v.u + 0x7FFF + ((v.u >> 16) & 1);   // RNE
    return (ushort)(r >> 16);
}
__device__ __forceinline__ float bf2f(ushort u) {
    union { unsigned u; float f; } v; v.u = ((unsigned)u) << 16;
    return v.f;
}
__device__ __forceinline__ void gload16(const void* g, void* l) {
    __builtin_amdgcn_global_load_lds((const __attribute__((address_space(1))) void*)g,
                                     (__attribute__((address_space(3))) void*)l, 16, 0, 0);
}
__device__ __forceinline__ uint4 glu8(uint4 a8, uint4 b8) {
    const ushort* ap = (const ushort*)&a8;
    const ushort* bp = (const ushort*)&b8;
    ushort r[8];
#pragma unroll
    for (int j = 0; j < 8; ++j) {
        float a = bf2f(ap[j]), b = bf2f(bp[j]);
        r[j] = f2bf(a * (b / (1.f + __expf(-b))));
    }
    return *(uint4*)r;
}

// ---------------- weight fp32 -> bf16 conversion ----------------
__global__ __launch_bounds__(256) void k_cvt(const float* __restrict__ s, ushort* __restrict__ d, int n8)
{
    int i = blockIdx.x * 256 + threadIdx.x;
    if (i >= n8) return;
    float4 x0 = ((const float4*)s)[i * 2];
    float4 x1 = ((const float4*)s)[i * 2 + 1];
    ushort r[8] = { f2bf(x0.x), f2bf(x0.y), f2bf(x0.z), f2bf(x0.w),
                    f2bf(x1.x), f2bf(x1.y), f2bf(x1.z), f2bf(x1.w) };
    ((uint4*)d)[i] = *(uint4*)r;
}

// ---------------- embedding: X fp32 + Xb bf16 ----------------
__global__ __launch_bounds__(256) void k_embed(const int* __restrict__ ids,
                                               const float* __restrict__ te,
                                               const float* __restrict__ pe,
                                               float* __restrict__ x,
                                               ushort* __restrict__ xb)
{
    int i = blockIdx.x * 256 + threadIdx.x;
    const int nd4 = DIMD / 4;
    if (i >= TOK * nd4) return;
    int t = i / nd4, d4 = i % nd4;
    int s = t % SEQ;
    int id = ids[t];
    float4 a = ((const float4*)(te + (size_t)id * DIMD))[d4];
    float4 b = ((const float4*)(pe + (size_t)s  * DIMD))[d4];
    float4 o; o.x = a.x + b.x; o.y = a.y + b.y; o.z = a.z + b.z; o.w = a.w + b.w;
    ((float4*)(x + (size_t)t * DIMD))[d4] = o;
    ushort4 ob = make_ushort4(f2bf(o.x), f2bf(o.y), f2bf(o.z), f2bf(o.w));
    *(ushort4*)(xb + (size_t)t * DIMD + d4 * 4) = ob;
}

// ---------------- unified MFMA GEMM: C = A x W^T + bias ----------------
// 128x128x32 tiles, bf16 A/W, LDS linear [128][32] double-buffered,
// global_load_lds(16B) staging, one barrier per K-step.
// GATHER: A rows via perm/toks (MoE W1). GLUA: A = glu(Hh row) reg-staged.
// CBF: C bf16 linear. SCAT: C fp32 scattered to F[token] (MoE W2).
template<int GATHER, int GLUA, int CBF, int SCAT>
__global__ __launch_bounds__(256) void k_mm(const ushort* __restrict__ A,
                                            const ushort* __restrict__ Wb,
                                            const float* __restrict__ bias,
                                            void* __restrict__ C_,
                                            int N, int K,
                                            const int* __restrict__ perm,
                                            const int* __restrict__ offs,
                                            const int* __restrict__ blke,
                                            const int* __restrict__ blkb,
                                            const int* __restrict__ nblk)
{
    constexpr int MOE = GATHER || SCAT;
    __shared__ ushort As[2][128 * 32];
    __shared__ ushort Bs[2][128 * 32];
    __shared__ int    toks[128];
    const int tid = threadIdx.x, lane = tid & 63, w = tid >> 6;
    const int rb = blockIdx.y;
    const int n0 = blockIdx.x * 128;
    const int row0 = rb * 128;
    const ushort* W = Wb;
    const float*  bi = bias;
    int lb = 0, cnt = 1 << 30;
    if constexpr (MOE) {
        if (rb >= *nblk) return;
        int e = blke[rb];
        lb = blkb[rb];
        int base = offs[e];
        cnt = offs[e + 1] - base;
        W  += (size_t)e * N * K;
        bi += (size_t)e * N;
        if (tid < 128) { int rg = lb + tid; toks[tid] = perm[base + (rg < cnt ? rg : cnt - 1)]; }
        __syncthreads();
    }
    // staging assignment: per wave, 16 rows per half; lane -> (row, 8-elem col)
    const int sr = lane >> 2;             // 0..15
    const int sc = (lane & 3) * 8;        // 0,8,16,24
    int ar0, ar1;
    if constexpr (GATHER) { ar0 = toks[w * 16 + sr]; ar1 = toks[64 + w * 16 + sr]; }
    else                  { ar0 = row0 + w * 16 + sr; ar1 = row0 + 64 + w * 16 + sr; }
    const int br0 = n0 + w * 16 + sr, br1 = n0 + 64 + w * 16 + sr;
    // GLU reg-staging assignment (64 rows per half, 8 elems)
    const int gsr = tid >> 2;             // 0..63
    const int gsc = (tid & 3) * 8;

    const int l15 = lane & 15, l4 = lane >> 4;
    const int wm = w >> 1, wn = w & 1;
    f32x4 acc[4][4] = {};

    // ---- prologue: stage tile 0 into buf 0 ----
    if constexpr (!GLUA) {
        gload16(A + (size_t)ar0 * K + sc, &As[0][(w * 16) * 32]);
        gload16(A + (size_t)ar1 * K + sc, &As[0][(64 + w * 16) * 32]);
    } else {
        uint4 a0 = *(const uint4*)(A + (size_t)(row0 + gsr) * 2 * K + gsc);
        uint4 b0 = *(const uint4*)(A + (size_t)(row0 + gsr) * 2 * K + K + gsc);
        uint4 a1 = *(const uint4*)(A + (size_t)(row0 + 64 + gsr) * 2 * K + gsc);
        uint4 b1 = *(const uint4*)(A + (size_t)(row0 + 64 + gsr) * 2 * K + K + gsc);
        *(uint4*)&As[0][gsr * 32 + gsc]        = glu8(a0, b0);
        *(uint4*)&As[0][(64 + gsr) * 32 + gsc] = glu8(a1, b1);
    }
    gload16(W + (size_t)br0 * K + sc, &Bs[0][(w * 16) * 32]);
    gload16(W + (size_t)br1 * K + sc, &Bs[0][(64 + w * 16) * 32]);
    __syncthreads();

    int cur = 0;
    const int NT = K / 32;
    for (int t = 0; t < NT; ++t) {
        const int nk = (t + 1) * 32;
        uint4 ga0, gb0, ga1, gb1;
        if (t + 1 < NT) {
            if constexpr (!GLUA) {
                gload16(A + (size_t)ar0 * K + nk + sc, &As[cur ^ 1][(w * 16) * 32]);
                gload16(A + (size_t)ar1 * K + nk + sc, &As[cur ^ 1][(64 + w * 16) * 32]);
            } else {
                ga0 = *(const uint4*)(A + (size_t)(row0 + gsr) * 2 * K + nk + gsc);
                gb0 = *(const uint4*)(A + (size_t)(row0 + gsr) * 2 * K + K + nk + gsc);
                ga1 = *(const uint4*)(A + (size_t)(row0 + 64 + gsr) * 2 * K + nk + gsc);
                gb1 = *(const uint4*)(A + (size_t)(row0 + 64 + gsr) * 2 * K + K + nk + gsc);
            }
            gload16(W + (size_t)br0 * K + nk + sc, &Bs[cur ^ 1][(w * 16) * 32]);
            gload16(W + (size_t)br1 * K + nk + sc, &Bs[cur ^ 1][(64 + w * 16) * 32]);
        }
        bf16x8 af[4], bf_[4];
#pragma unroll
        for (int i = 0; i < 4; ++i) {
            af[i]  = *(const bf16x8*)&As[cur][(wm * 64 + i * 16 + l15) * 32 + l4 * 8];
            bf_[i] = *(const bf16x8*)&Bs[cur][(wn * 64 + i * 16 + l15) * 32 + l4 * 8];
        }
#pragma unroll
        for (int mi = 0; mi < 4; ++mi)
#pragma unroll
            for (int ni = 0; ni < 4; ++ni)
                acc[mi][ni] = __builtin_amdgcn_mfma_f32_16x16x32_bf16(af[mi], bf_[ni], acc[mi][ni], 0, 0, 0);
        if (t + 1 < NT) {
            if constexpr (GLUA) {
                *(uint4*)&As[cur ^ 1][gsr * 32 + gsc]        = glu8(ga0, gb0);
                *(uint4*)&As[cur ^ 1][(64 + gsr) * 32 + gsc] = glu8(ga1, gb1);
            }
        }
        __syncthreads();
        cur ^= 1;
    }
    // ---- epilogue ----
#pragma unroll
    for (int ni = 0; ni < 4; ++ni) {
        int col = n0 + wn * 64 + ni * 16 + l15;
        float bb = bi[col];
#pragma unroll
        for (int mi = 0; mi < 4; ++mi) {
            int ri = wm * 64 + mi * 16 + l4 * 4;
#pragma unroll
            for (int r = 0; r < 4; ++r) {
                float o = acc[mi][ni][r] + bb;
                if constexpr (SCAT) {
                    if (lb + ri + r < cnt)
                        ((float*)C_)[(size_t)toks[ri + r] * N + col] = o;
                } else if constexpr (CBF) {
                    ((ushort*)C_)[(size_t)(row0 + ri + r) * N + col] = f2bf(o);
                } else {
                    ((float*)C_)[(size_t)(row0 + ri + r) * N + col] = o;
                }
            }
        }
    }
}

// ---------------- MFMA flash attention ----------------
__global__ __launch_bounds__(256) void k_attn(const ushort* __restrict__ qkv, ushort* __restrict__ out)
{
    __shared__ ushort Qs[64][72];
    __shared__ ushort Ks[64][72];
    __shared__ ushort Vt[64][72];
    __shared__ ushort Ps[4][16][72];
    const int bh = blockIdx.x;
    const int b = bh / NH, h = bh % NH;
    const int qt = blockIdx.y;
    const int tid = threadIdx.x, lane = tid & 63, w = tid >> 6;
    const int l15 = lane & 15, l4 = lane >> 4;
    const int t0 = b * SEQ + qt * 64;
    {
        int r = tid >> 3, c8 = (tid & 7) * 8;
#pragma unroll
        for (int p = 0; p < 2; ++p) {
            int rr = r + p * 32;
            *(uint4*)&Qs[rr][c8] = *(const uint4*)(qkv + (size_t)(t0 + rr) * 3 * DIMD + h * DHD + c8);
        }
    }
    __syncthreads();
    bf16x8 aq[2];
    aq[0] = *(const bf16x8*)&Qs[w*16 + l15][l4*8];
    aq[1] = *(const bf16x8*)&Qs[w*16 + l15][32 + l4*8];
    f32x4 o[4] = {};
    float m[4], lsum[4];
#pragma unroll
    for (int r = 0; r < 4; ++r) { m[r] = -3.0e38f; lsum[r] = 0.f; }
    for (int kt = 0; kt < SEQ; kt += 64) {
        __syncthreads();
        {
            int r = tid >> 3, c8 = (tid & 7) * 8;
#pragma unroll
            for (int p = 0; p < 2; ++p) {
                int rr = r + p * 32;
                const ushort* kp = qkv + (size_t)(b * SEQ + kt + rr) * 3 * DIMD + DIMD + h * DHD;
                *(uint4*)&Ks[rr][c8] = *(const uint4*)(kp + c8);
                uint4 vv = *(const uint4*)(kp + DIMD + c8);
                const ushort* vs = (const ushort*)&vv;
#pragma unroll
                for (int j = 0; j < 8; ++j) Vt[c8 + j][rr] = vs[j];
            }
        }
        __syncthreads();
        f32x4 s[4] = {};
#pragma unroll
        for (int kk = 0; kk < 2; ++kk)
#pragma unroll
            for (int ni = 0; ni < 4; ++ni) {
                bf16x8 bk = *(const bf16x8*)&Ks[ni*16 + l15][kk*32 + l4*8];
                s[ni] = __builtin_amdgcn_mfma_f32_16x16x32_bf16(aq[kk], bk, s[ni], 0, 0, 0);
            }
        float csc[4];
#pragma unroll
        for (int r = 0; r < 4; ++r) {
            float mx = -3.0e38f;
#pragma unroll
            for (int ni = 0; ni < 4; ++ni) { s[ni][r] *= 0.125f; mx = fmaxf(mx, s[ni][r]); }
            mx = fmaxf(mx, __shfl_xor(mx, 1));
            mx = fmaxf(mx, __shfl_xor(mx, 2));
            mx = fmaxf(mx, __shfl_xor(mx, 4));
            mx = fmaxf(mx, __shfl_xor(mx, 8));
            float nm = fmaxf(m[r], mx);
            float c = __expf(m[r] - nm);
            m[r] = nm;
            float ps = 0.f;
#pragma unroll
            for (int ni = 0; ni < 4; ++ni) { s[ni][r] = __expf(s[ni][r] - nm); ps += s[ni][r]; }
            ps += __shfl_xor(ps, 1);
            ps += __shfl_xor(ps, 2);
            ps += __shfl_xor(ps, 4);
            ps += __shfl_xor(ps, 8);
            lsum[r] = lsum[r] * c + ps;
            csc[r] = c;
#pragma unroll
            for (int ni = 0; ni < 4; ++ni)
                Ps[w][l4*4 + r][ni*16 + l15] = f2bf(s[ni][r]);
        }
#pragma unroll
        for (int di = 0; di < 4; ++di)
#pragma unroll
            for (int r = 0; r < 4; ++r) o[di][r] *= csc[r];
        bf16x8 ap[2];
        ap[0] = *(const bf16x8*)&Ps[w][l15][l4*8];
        ap[1] = *(const bf16x8*)&Ps[w][l15][32 + l4*8];
#pragma unroll
        for (int kk = 0; kk < 2; ++kk)
#pragma unroll
            for (int di = 0; di < 4; ++di) {
                bf16x8 bv = *(const bf16x8*)&Vt[di*16 + l15][kk*32 + l4*8];
                o[di] = __builtin_amdgcn_mfma_f32_16x16x32_bf16(ap[kk], bv, o[di], 0, 0, 0);
            }
    }
    float inv[4];
#pragma unroll
    for (int r = 0; r < 4; ++r) inv[r] = 1.f / lsum[r];
#pragma unroll
    for (int di = 0; di < 4; ++di)
#pragma unroll
        for (int r = 0; r < 4; ++r)
            out[(size_t)(t0 + w*16 + l4*4 + r) * DIMD + h * DHD + di*16 + l15] = f2bf(o[di][r] * inv[r]);
}

// ---------------- fused residual + LayerNorm -> X fp32 + Xb bf16 ----------------
__global__ __launch_bounds__(256) void k_ln(float* __restrict__ x, const float* __restrict__ f,
                                            const float* __restrict__ g, const float* __restrict__ b,
                                            ushort* __restrict__ xb)
{
    const int t = blockIdx.x, tid = threadIdx.x;
    __shared__ float y[DIMD];
    __shared__ float red[256];
    float* xr = x + (size_t)t * DIMD;
    const float* fr = f + (size_t)t * DIMD;
    float s = 0.f;
    for (int d = tid; d < DIMD; d += 256) { float v = xr[d] + fr[d]; y[d] = v; s += v; }
    red[tid] = s; __syncthreads();
    for (int off = 128; off > 0; off >>= 1) { if (tid < off) red[tid] += red[tid + off]; __syncthreads(); }
    const float mean = red[0] * (1.f / DIMD);
    __syncthreads();
    s = 0.f;
    for (int d = tid; d < DIMD; d += 256) { float v = y[d] - mean; s += v * v; }
    red[tid] = s; __syncthreads();
    for (int off = 128; off > 0; off >>= 1) { if (tid < off) red[tid] += red[tid + off]; __syncthreads(); }
    const float rstd = 1.f / sqrtf(red[0] * (1.f / DIMD) + 1e-5f);
    for (int d = tid; d < DIMD; d += 256) {
        float v = (y[d] - mean) * rstd * g[d] + b[d];
        xr[d] = v;
        xb[(size_t)t * DIMD + d] = f2bf(v);
    }
}

// ---------------- MoE gating ----------------
__global__ __launch_bounds__(256) void k_gate(const float* __restrict__ x,
                                              const float* __restrict__ gAw, const float* __restrict__ gAb,
                                              const float* __restrict__ gBw, const float* __restrict__ gBb,
                                              float* __restrict__ sums, int* __restrict__ cnts,
                                              int* __restrict__ e_id)
{
    const int tid = threadIdx.x, lane = tid & 63, wid = tid >> 6;
    const int gw = blockIdx.x * 4 + wid;
    float wA0[12], wA1[12], wB0[12], wB1[12];
#pragma unroll
    for (int i = 0; i < 12; ++i) {
        int d = lane + i * 64;
        wA0[i] = gAw[d]; wA1[i] = gAw[DIMD + d];
        wB0[i] = gBw[d]; wB1[i] = gBw[DIMD + d];
    }
    const float bA0 = gAb[0], bA1 = gAb[1], bB0 = gBb[0], bB1 = gBb[1];
    float sA0 = 0.f, sA1 = 0.f, sB0 = 0.f, sB1 = 0.f;
    int cA1 = 0, cB1 = 0, cE0 = 0, cE1 = 0, cE2 = 0;
    for (int i = 0; i < 32; ++i) {
        int t = gw * 32 + i;
        const float* xr = x + (size_t)t * DIMD;
        float a0 = 0.f, a1 = 0.f, b0 = 0.f, b1 = 0.f;
#pragma unroll
        for (int j = 0; j < 12; ++j) {
            float v = xr[lane + j * 64];
            a0 = fmaf(v, wA0[j], a0); a1 = fmaf(v, wA1[j], a1);
            b0 = fmaf(v, wB0[j], b0); b1 = fmaf(v, wB1[j], b1);
        }
#pragma unroll
        for (int off = 1; off < 64; off <<= 1) {
            a0 += __shfl_xor(a0, off); a1 += __shfl_xor(a1, off);
            b0 += __shfl_xor(b0, off); b1 += __shfl_xor(b1, off);
        }
        a0 += bA0; a1 += bA1; b0 += bB0; b1 += bB1;
        int iA = (a1 > a0) ? 1 : 0;
        int iB = (b1 > b0) ? 1 : 0;
        float mA = fmaxf(a0, a1); float eA0 = __expf(a0 - mA), eA1 = __expf(a1 - mA);
        float dA = 1.f / (eA0 + eA1);
        float mB = fmaxf(b0, b1); float eB0 = __expf(b0 - mB), eB1 = __expf(b1 - mB);
        float dB = 1.f / (eB0 + eB1);
        sA0 += eA0 * dA; sA1 += eA1 * dA;
        sB0 += eB0 * dB; sB1 += eB1 * dB;
        cA1 += iA; cB1 += iB;
        int e = iA * 2 + iB;
        cE0 += (e == 0); cE1 += (e == 1); cE2 += (e == 2);
        if (lane == 0) e_id[t] = e;
    }
    __shared__ float fpart[4][4];
    __shared__ int   ipart[4][8];
    if (lane == 0) {
        fpart[wid][0] = sA0; fpart[wid][1] = sA1; fpart[wid][2] = sB0; fpart[wid][3] = sB1;
        ipart[wid][0] = 32 - cA1; ipart[wid][1] = cA1;
        ipart[wid][2] = 32 - cB1; ipart[wid][3] = cB1;
        ipart[wid][4] = cE0; ipart[wid][5] = cE1; ipart[wid][6] = cE2;
        ipart[wid][7] = 32 - cE0 - cE1 - cE2;
    }
    __syncthreads();
    if (tid < 4)  atomicAdd(sums + tid, fpart[0][tid] + fpart[1][tid] + fpart[2][tid] + fpart[3][tid]);
    else if (tid >= 64 && tid < 72) {
        int k = tid - 64;
        atomicAdd(cnts + k, ipart[0][k] + ipart[1][k] + ipart[2][k] + ipart[3][k]);
    }
}

__global__ void k_offsets(const int* __restrict__ cntE, int* __restrict__ offs, int* __restrict__ cursor,
                          int* __restrict__ nblk, int* __restrict__ blke, int* __restrict__ blkb)
{
    if (threadIdx.x == 0) {
        int a = 0, nb = 0;
        for (int e = 0; e < NEXP; ++e) {
            offs[e] = a; a += cntE[e]; cursor[e] = 0;
            int blocks = (cntE[e] + 127) >> 7;
            for (int b = 0; b < blocks; ++b) { blke[nb] = e; blkb[nb] = b * 128; ++nb; }
        }
        offs[NEXP] = a;
        *nblk = nb;
    }
}

__global__ __launch_bounds__(256) void k_scatter(const int* __restrict__ e_id, const int* __restrict__ offs,
                                                 int* __restrict__ cursor, int* __restrict__ perm)
{
    int t = blockIdx.x * 256 + threadIdx.x;
    int lane = threadIdx.x & 63;
    int e = e_id[t];
#pragma unroll
    for (int eo = 0; eo < NEXP; ++eo) {
        unsigned long long m = __ballot(e == eo);
        if (m == 0ULL) continue;
        int leader = __ffsll((long long)m) - 1;
        int base = 0;
        if (lane == leader) base = atomicAdd(cursor + eo, (int)__popcll(m));
        base = __shfl(base, leader);
        if (e == eo) {
            int lower = (int)__popcll(m & ((1ULL << lane) - 1ULL));
            perm[offs[eo] + base + lower] = t;
        }
    }
}

__global__ void k_aux(const float* __restrict__ sums, const int* __restrict__ cnts, float* __restrict__ aux_acc)
{
    if (threadIdx.x == 0) {
        const float invT2 = 1.f / ((float)TOK * (float)TOK);
        float aA = 2.f * (sums[0] * (float)cnts[0] + sums[1] * (float)cnts[1]) * invT2;
        float aB = 2.f * (sums[2] * (float)cnts[2] + sums[3] * (float)cnts[3]) * invT2;
        *aux_acc += aA + aB;
    }
}

// ---------------- classifier head ----------------
__global__ __launch_bounds__(256) void k_rep(const float* __restrict__ x, float* __restrict__ rep)
{
    int i = blockIdx.x * 256 + threadIdx.x;
    if (i >= NB_ * DIMD) return;
    int b = i / DIMD, d = i % DIMD;
    float s = 0.f;
    for (int q = 0; q < SEQ; ++q) s += x[((size_t)b * SEQ + q) * DIMD + d];
    rep[i] = s * (1.f / SEQ);
}

__global__ __launch_bounds__(256) void k_cls1(const float* __restrict__ rep, const float* __restrict__ cW1,
                                              const float* __restrict__ cB1, float* __restrict__ hcls)
{
    int w = blockIdx.x * 4 + (threadIdx.x >> 6);
    int lane = threadIdx.x & 63;
    if (w >= NB_ * DIMD) return;
    int b = w / DIMD, i = w % DIMD;
    float s = 0.f;
    for (int d = lane; d < DIMD; d += 64) s += rep[b * DIMD + d] * cW1[(size_t)i * DIMD + d];
    for (int off = 32; off > 0; off >>= 1) s += __shfl_down(s, off);
    if (lane == 0) hcls[w] = fmaxf(s + cB1[i], 0.f);
}

__global__ __launch_bounds__(256) void k_cls2(const float* __restrict__ hcls, const float* __restrict__ cW2,
                                              const float* __restrict__ cB2, float* __restrict__ out)
{
    int w = blockIdx.x * 4 + (threadIdx.x >> 6);
    int lane = threadIdx.x & 63;
    if (w >= NB_ * CCLS) return;
    int b = w / CCLS, c = w % CCLS;
    float s = 0.f;
    for (int d = lane; d < DIMD; d += 64) s += hcls[b * DIMD + d] * cW2[(size_t)c * DIMD + d];
    for (int off = 32; off > 0; off >>= 1) s += __shfl_down(s, off);
    if (lane == 0) out[w] = s + cB2[c];
}

__global__ void k_writeaux(const float* __restrict__ aux_acc, float* __restrict__ out)
{
    if (threadIdx.x == 0) out[NB_ * CCLS] = *aux_acc;
}

// ---------------- host launch ----------------
extern "C" void kernel_launch(void* const* d_in, const int* in_sizes, int n_in,
                              void* d_out, int out_size, void* d_ws, size_t ws_size,
                              hipStream_t stream)
{
    const int*   input_ids = (const int*)  d_in[0];
    const float* tok_emb   = (const float*)d_in[1];
    const float* pos_emb   = (const float*)d_in[2];
    const float* wqkv      = (const float*)d_in[3];
    const float* bqkv      = (const float*)d_in[4];
    const float* wo        = (const float*)d_in[5];
    const float* bo        = (const float*)d_in[6];
    const float* ln1g      = (const float*)d_in[7];
    const float* ln1b      = (const float*)d_in[8];
    const float* ln2g      = (const float*)d_in[9];
    const float* ln2b      = (const float*)d_in[10];
    const float* dW1       = (const float*)d_in[11];
    const float* dB1       = (const float*)d_in[12];
    const float* dW2       = (const float*)d_in[13];
    const float* dB2       = (const float*)d_in[14];
    const float* mW1       = (const float*)d_in[15];
    const float* mB1       = (const float*)d_in[16];
    const float* mW2       = (const float*)d_in[17];
    const float* mB2       = (const float*)d_in[18];
    const float* gAw       = (const float*)d_in[19];
    const float* gAb       = (const float*)d_in[20];
    const float* gBw       = (const float*)d_in[21];
    const float* gBb       = (const float*)d_in[22];
    const float* cW1       = (const float*)d_in[23];
    const float* cB1       = (const float*)d_in[24];
    const float* cW2       = (const float*)d_in[25];
    const float* cB2       = (const float*)d_in[26];

    float* out = (float*)d_out;
    float* ws  = (float*)d_ws;

    float*  X    = ws + OFF_X;
    ushort* XB   = (ushort*)(ws + OFF_XB);
    float*  F    = ws + OFF_F;
    ushort* QKV  = (ushort*)(ws + OFF_SH);
    ushort* G    = (ushort*)(ws + OFF_SH + (size_t)TOK * 3 * DIMD / 2);
    ushort* Hh   = (ushort*)(ws + OFF_SH);
    ushort* WQB  = (ushort*)(ws + OFF_WQ);
    ushort* WOB  = (ushort*)(ws + OFF_WOB);
    ushort* W1B  = (ushort*)(ws + OFF_W1B);
    ushort* W2B  = (ushort*)(ws + OFF_W2B);
    float*  REP  = ws + OFF_REP;
    float*  HCLS = ws + OFF_HCLS;
    float*  SUMS = ws + OFF_STAT;
    int*    INTB = (int*)(ws + OFF_INT);
    int*    CNTS = INTB;            // 8
    int*    OFFS = INTB + 8;        // 5
    int*    CURS = INTB + 13;       // 4
    int*    NBLK = INTB + 17;       // 1
    int*    BLKE = INTB + 18;       // 68
    int*    BLKB = INTB + 86;      // 68
    float*  AUXP = ws + OFF_AUX;
    int*    EID  = (int*)(ws + OFF_EID);
    int*    PERM = (int*)(ws + OFF_PERM);

    hipMemsetAsync(AUXP, 0, sizeof(float), stream);

    k_embed<<<dim3((TOK * DIMD / 4) / 256), 256, 0, stream>>>(input_ids, tok_emb, pos_emb, X, XB);

    int di = 0, mi = 0;
    for (int l = 0; l < 6; ++l) {
        const int moe = (l == 1 || l == 3 || l == 5);
        // --- per-layer weight conversion fp32->bf16 ---
        {
            int n8 = 3 * DIMD * DIMD / 8;
            k_cvt<<<dim3((n8 + 255) / 256), 256, 0, stream>>>(wqkv + (size_t)l * 3 * DIMD * DIMD, WQB, n8);
            n8 = DIMD * DIMD / 8;
            k_cvt<<<dim3((n8 + 255) / 256), 256, 0, stream>>>(wo + (size_t)l * DIMD * DIMD, WOB, n8);
            if (moe) {
                n8 = NEXP * FF2 * DIMD / 8;
                k_cvt<<<dim3((n8 + 255) / 256), 256, 0, stream>>>(mW1 + (size_t)mi * NEXP * FF2 * DIMD, W1B, n8);
                n8 = NEXP * DIMD * FFD / 8;
                k_cvt<<<dim3((n8 + 255) / 256), 256, 0, stream>>>(mW2 + (size_t)mi * NEXP * DIMD * FFD, W2B, n8);
            } else {
                n8 = FF2 * DIMD / 8;
                k_cvt<<<dim3((n8 + 255) / 256), 256, 0, stream>>>(dW1 + (size_t)di * FF2 * DIMD, W1B, n8);
                n8 = DIMD * FFD / 8;
                k_cvt<<<dim3((n8 + 255) / 256), 256, 0, stream>>>(dW2 + (size_t)di * DIMD * FFD, W2B, n8);
            }
        }
        // QKV projection (bf16 -> bf16)
        k_mm<0,0,1,0><<<dim3(3 * DIMD / 128, TOK / 128), 256, 0, stream>>>(
            XB, WQB, bqkv + (size_t)l * 3 * DIMD, QKV, 3 * DIMD, DIMD,
            nullptr, nullptr, nullptr, nullptr, nullptr);
        // attention
        k_attn<<<dim3(NB_ * NH, SEQ / 64), 256, 0, stream>>>(QKV, G);
        // output projection (bf16 -> fp32 F)
        k_mm<0,0,0,0><<<dim3(DIMD / 128, TOK / 128), 256, 0, stream>>>(
            G, WOB, bo + (size_t)l * DIMD, F, DIMD, DIMD,
            nullptr, nullptr, nullptr, nullptr, nullptr);
        k_ln<<<TOK, 256, 0, stream>>>(X, F, ln1g + (size_t)l * DIMD, ln1b + (size_t)l * DIMD, XB);

        if (moe) {
            hipMemsetAsync(SUMS, 0, 64, stream);
            k_gate<<<64, 256, 0, stream>>>(X,
                gAw + (size_t)mi * 2 * DIMD, gAb + (size_t)mi * 2,
                gBw + (size_t)mi * 2 * DIMD, gBb + (size_t)mi * 2,
                SUMS, CNTS, EID);
            k_offsets<<<1, 1, 0, stream>>>(CNTS + 4, OFFS, CURS, NBLK, BLKE, BLKB);
            k_scatter<<<TOK / 256, 256, 0, stream>>>(EID, OFFS, CURS, PERM);
            k_mm<1,0,1,0><<<dim3(FF2 / 128, 67), 256, 0, stream>>>(
                XB, W1B, mB1 + (size_t)mi * NEXP * FF2, Hh, FF2, DIMD,
                PERM, OFFS, BLKE, BLKB, NBLK);
            k_mm<0,1,0,1><<<dim3(DIMD / 128, 67), 256, 0, stream>>>(
                Hh, W2B, mB2 + (size_t)mi * NEXP * DIMD, F, DIMD, FFD,
                PERM, OFFS, BLKE, BLKB, NBLK);
            k_aux<<<1, 1, 0, stream>>>(SUMS, CNTS, AUXP);
            ++mi;
        } else {
            k_mm<0,0,1,0><<<dim3(FF2 / 128, TOK / 128), 256, 0, stream>>>(
                XB, W1B, dB1 + (size_t)di * FF2, Hh, FF2, DIMD,
                nullptr, nullptr, nullptr, nullptr, nullptr);
            k_mm<0,1,0,0><<<dim3(DIMD / 128, TOK / 128), 256, 0, stream>>>(
                Hh, W2B, dB2 + (size_t)di * DIMD, F, DIMD, FFD,
                nullptr, nullptr, nullptr, nullptr, nullptr);
            ++di;
        }
        k_ln<<<TOK, 256, 0, stream>>>(X, F, ln2g + (size_t)l * DIMD, ln2b + (size_t)l * DIMD, XB);
    }

    k_rep<<<dim3((NB_ * DIMD + 255) / 256), 256, 0, stream>>>(X, REP);
    k_cls1<<<dim3(NB_ * DIMD / 4), 256, 0, stream>>>(REP, cW1, cB1, HCLS);
    k_cls2<<<dim3((NB_ * CCLS + 3) / 4), 256, 0, stream>>>(HCLS, cW2, cB2, out);
    k_writeaux<<<1, 1, 0, stream>>>(AUXP, out);
}